// Round 18
// baseline (91.366 us; speedup 1.0000x reference)
//
#include <hip/hip_runtime.h>

#define IN_CH 128
#define HID 64
#define ELLW 32        // 32 x ushort = 64B per node row
#define SPILLCAP 4096  // overflow edges (P ~ 0 for this graph)
#define NSCAT 64       // blocks carrying scatter duty
#define BCAP 3584      // fixed region capacity per 256-node bucket (mean 3061, +9 sigma)

typedef short v8s __attribute__((ext_vector_type(8)));   // 8 bf16 (4 VGPRs)
typedef float v4f __attribute__((ext_vector_type(4)));   // 4 f32 acc

// branch-free f32 -> bf16 (round-to-nearest-even), pure uint math
__device__ __forceinline__ unsigned int bf16pair(float a, float b) {
    unsigned int ua = __float_as_uint(a);
    unsigned int ub = __float_as_uint(b);
    ua = (ua + 0x7fffu + ((ua >> 16) & 1u)) >> 16;          // elem0 -> low 16
    ub = (ub + 0x7fffu + ((ub >> 16) & 1u)) & 0xffff0000u;  // elem1 -> high 16
    return ua | ub;
}
__device__ __forceinline__ unsigned short bf16of(float a) {
    unsigned int ua = __float_as_uint(a);
    return (unsigned short)((ua + 0x7fffu + ((ua >> 16) & 1u)) >> 16);
}

// ---------------------------------------------------------------------------
// Kernel 1: MFMA encoder (R6's proven tile) + co-resident bucket scatter.
// 512 threads, 64 nodes/block, grid 782 >= NSCAT.
//   t<256 : stage As (x->bf16) + Bs ([W_rel|W_root]^T bf16); 32 MFMAs/wave;
//           epilogue y16 (bf16) + agg (f32, +b_rel).
//   t>=256: blocks 0..NSCAT-1 only — zero lh/lcur; hist; reserve; write.
// Barriers: B1 (staging done / lh zeroed), B2 (hist done), B3 (cursors set).
// Rationale: R16/R17 counters prove the VALU tile is LDS-throughput-bound
// (VALUBusy pinned ~39%, 8 ds_read_b128 per 64 FMA x 12 waves/CU = 3x LDS
// oversubscription). MFMA amortizes LDS reads over 16x16x32 FLOPs.
// ---------------------------------------------------------------------------
__global__ __launch_bounds__(512) void graphmae_encode_scatter(
    const float* __restrict__ x, const float* __restrict__ W_rel,
    const float* __restrict__ b_rel, const float* __restrict__ W_root,
    const int* __restrict__ ei,
    unsigned short* __restrict__ y16, float* __restrict__ agg,
    int* __restrict__ bucketcur, unsigned int* __restrict__ sorted,
    int* __restrict__ spillcnt, int2* __restrict__ spill,
    int N, int E, int NBUK, int CE)
{
    __shared__ unsigned short As[64][136];    // x tile, bf16
    __shared__ unsigned short Bs[128][136];   // [W_rel|W_root]^T, bf16: [col][k]
    __shared__ int lh[256];                   // scatter: per-bucket local count
    __shared__ int lcur[256];                 // scatter: base -> running cursor

    const int t  = threadIdx.x;
    const int n0 = blockIdx.x * 64;
    const bool sduty = (blockIdx.x < NSCAT);
    const int e0 = blockIdx.x * CE;
    const int e1 = sduty ? min(E, e0 + CE) : 0;

    if (t < 256) {
        // ---- stage x -> As (bf16): 4 threads/row, 8 float4 each ----
        {
            const int r = t >> 2, q = t & 3;
            const int n = n0 + r;
            unsigned short* ap = &As[r][q * 32];
            if (n < N) {
                const float* xp = x + (size_t)n * IN_CH + q * 32;
                #pragma unroll
                for (int j = 0; j < 8; ++j) {
                    const float4 v = *(const float4*)(xp + j * 4);
                    *(uint2*)(ap + j * 4) =
                        make_uint2(bf16pair(v.x, v.y), bf16pair(v.z, v.w));
                }
            } else {
                #pragma unroll
                for (int j = 0; j < 8; ++j) *(uint2*)(ap + j * 4) = make_uint2(0u, 0u);
            }
        }
        // ---- stage weights -> Bs transposed (bf16) ----
        #pragma unroll
        for (int p = 0; p < 16; ++p) {
            const int idx = t + p * 256;        // float4 id 0..4095
            const int k   = idx >> 5;           // 0..127
            const int c4  = (idx & 31) * 4;     // 0..124
            float4 v;
            if (c4 < HID) v = *(const float4*)(W_rel  + (size_t)k * HID + c4);
            else          v = *(const float4*)(W_root + (size_t)k * HID + (c4 - HID));
            Bs[c4 + 0][k] = bf16of(v.x);
            Bs[c4 + 1][k] = bf16of(v.y);
            Bs[c4 + 2][k] = bf16of(v.z);
            Bs[c4 + 3][k] = bf16of(v.w);
        }
    } else {
        lh[t - 256] = 0;
        lcur[t - 256] = 0;
    }
    __syncthreads();   // B1: staging done / lh zeroed

    if (t < 256) {
        const int w    = t >> 6;
        const int lane = t & 63;
        const int mr   = lane & 15;
        const int kg   = lane >> 4;

        v8s afrag[4];
        #pragma unroll
        for (int ks = 0; ks < 4; ++ks)
            afrag[ks] = *(const v8s*)(&As[w * 16 + mr][ks * 32 + kg * 8]);

        const int rbase = n0 + w * 16 + kg * 4;   // C/D: row = kg*4 + reg
        #pragma unroll
        for (int ct = 0; ct < 8; ++ct) {
            v4f acc = {0.f, 0.f, 0.f, 0.f};
            #pragma unroll
            for (int ks = 0; ks < 4; ++ks) {
                const v8s b = *(const v8s*)(&Bs[ct * 16 + mr][ks * 32 + kg * 8]);
                acc = __builtin_amdgcn_mfma_f32_16x16x32_bf16(afrag[ks], b, acc, 0, 0, 0);
            }
            const int c = ct * 16 + mr;           // C/D: col = lane&15
            if (ct < 4) {
                #pragma unroll
                for (int r = 0; r < 4; ++r) {
                    const int n = rbase + r;
                    if (n < N) y16[(size_t)n * HID + c] = bf16of(acc[r]);
                }
            } else {
                const float br = b_rel[c - HID];
                #pragma unroll
                for (int r = 0; r < 4; ++r) {
                    const int n = rbase + r;
                    if (n < N) agg[(size_t)n * HID + (c - HID)] = acc[r] + br;
                }
            }
        }
    } else if (sduty) {
        // ---- hist: LDS atomics over the block's edge chunk ----
        for (int e = e0 + (t - 256); e < e1; e += 256)
            atomicAdd(&lh[ei[E + e] >> 8], 1);
    }
    __syncthreads();   // B2: hist complete

    if (t >= 256 && sduty) {
        // ---- reserve: one returned global atomic per (block,bucket) ----
        const int b = t - 256;
        if (b < NBUK) {
            const int cnt = lh[b];
            if (cnt > 0) lcur[b] = atomicAdd(&bucketcur[b], cnt);
        }
    }
    __syncthreads();   // B3: cursors ready

    if (t >= 256 && sduty) {
        // ---- write: packed edges at LDS cursor positions ----
        for (int e = e0 + (t - 256); e < e1; e += 256) {
            const int d = ei[E + e];
            const int s = ei[e];
            const int b = d >> 8;
            const int pos = atomicAdd(&lcur[b], 1);
            if (pos < BCAP) {
                sorted[(size_t)b * BCAP + pos] =
                    ((unsigned)(d & 255) << 16) | (unsigned)s;
            } else {
                const int p = atomicAdd(spillcnt, 1);   // statistically never
                if (p < SPILLCAP) spill[p] = make_int2(d, s);
            }
        }
    }
}

// ---------------------------------------------------------------------------
// Kernel 2: per-bucket ELL fill, entirely in LDS; coalesced 16KB writeout.
// Writes deg for EVERY padded node (no pre-zero needed).
// ---------------------------------------------------------------------------
__global__ __launch_bounds__(256) void bucket_fill(
    const unsigned int* __restrict__ sorted, const int* __restrict__ bucketcur,
    int* __restrict__ deg, unsigned short* __restrict__ slots16,
    int* __restrict__ spillcnt, int2* __restrict__ spill)
{
    __shared__ int cnt[256];
    __shared__ unsigned short sl[256 * ELLW];   // 16KB
    const int t = threadIdx.x, b = blockIdx.x;
    cnt[t] = 0;
    __syncthreads();

    const int m = min(bucketcur[b], BCAP);
    const unsigned int* src = sorted + (size_t)b * BCAP;
    for (int i = t; i < m; i += 256) {
        const unsigned int v = src[i];
        const int dl = v >> 16;
        const int r = atomicAdd(&cnt[dl], 1);       // LDS atomic — fast
        if (r < ELLW) sl[dl * ELLW + r] = (unsigned short)(v & 0xffffu);
        else {
            const int p = atomicAdd(spillcnt, 1);   // statistically never
            if (p < SPILLCAP) spill[p] = make_int2((b << 8) + dl, (int)(v & 0xffffu));
        }
    }
    __syncthreads();

    deg[(b << 8) + t] = cnt[t];
    unsigned int* g = (unsigned int*)slots16 + (size_t)b * 4096;
    const unsigned int* l = (const unsigned int*)sl;
    for (int i = t; i < 4096; i += 256) g[i] = l[i];
}

// ---------------------------------------------------------------------------
// Kernel 3: gather (proven R10-R17 structure). One wave64 per node,
// 8 edge-slots x 8 col-lanes. h = relu(agg + sum) stored bf16.
// ---------------------------------------------------------------------------
__global__ __launch_bounds__(256) void graphmae_gather(
    const int* __restrict__ deg, const unsigned short* __restrict__ slots16,
    const unsigned short* __restrict__ y16, const float* __restrict__ agg,
    const int* __restrict__ spillcnt, const int2* __restrict__ spill,
    unsigned short* __restrict__ h16, int N)
{
    const int n = blockIdx.x * 4 + (threadIdx.x >> 6);
    if (n >= N) return;
    const int lane = threadIdx.x & 63;
    const int es   = lane >> 3;
    const int cl   = lane & 7;

    const int cnt = min(deg[n], ELLW);
    const unsigned short* sp = slots16 + (size_t)n * ELLW;

    float4 a0 = make_float4(0.f, 0.f, 0.f, 0.f);
    float4 a1 = make_float4(0.f, 0.f, 0.f, 0.f);
    if (es == 0) {
        a0 = *(const float4*)(agg + (size_t)n * HID + cl * 8);
        a1 = *(const float4*)(agg + (size_t)n * HID + cl * 8 + 4);
    }

    float acc[8];
    #pragma unroll
    for (int j = 0; j < 8; ++j) acc[j] = 0.f;

    for (int e = es; e < cnt; e += 8) {
        const int s = sp[e];
        const uint4 v = *(const uint4*)(y16 + (size_t)s * HID + cl * 8);
        acc[0] += __uint_as_float(v.x << 16);
        acc[1] += __uint_as_float(v.x & 0xffff0000u);
        acc[2] += __uint_as_float(v.y << 16);
        acc[3] += __uint_as_float(v.y & 0xffff0000u);
        acc[4] += __uint_as_float(v.z << 16);
        acc[5] += __uint_as_float(v.z & 0xffff0000u);
        acc[6] += __uint_as_float(v.w << 16);
        acc[7] += __uint_as_float(v.w & 0xffff0000u);
    }

    const int spN = min(*spillcnt, SPILLCAP);
    for (int i = es; i < spN; i += 8) {
        const int2 e2 = spill[i];
        if (e2.x == n) {
            const uint4 v = *(const uint4*)(y16 + (size_t)e2.y * HID + cl * 8);
            acc[0] += __uint_as_float(v.x << 16);
            acc[1] += __uint_as_float(v.x & 0xffff0000u);
            acc[2] += __uint_as_float(v.y << 16);
            acc[3] += __uint_as_float(v.y & 0xffff0000u);
            acc[4] += __uint_as_float(v.z << 16);
            acc[5] += __uint_as_float(v.z & 0xffff0000u);
            acc[6] += __uint_as_float(v.w << 16);
            acc[7] += __uint_as_float(v.w & 0xffff0000u);
        }
    }

    #pragma unroll
    for (int m = 8; m <= 32; m <<= 1) {
        #pragma unroll
        for (int j = 0; j < 8; ++j) acc[j] += __shfl_xor(acc[j], m);
    }

    if (es == 0) {
        const float h0 = fmaxf(a0.x + acc[0], 0.f);
        const float h1 = fmaxf(a0.y + acc[1], 0.f);
        const float h2 = fmaxf(a0.z + acc[2], 0.f);
        const float h3 = fmaxf(a0.w + acc[3], 0.f);
        const float h4 = fmaxf(a1.x + acc[4], 0.f);
        const float h5 = fmaxf(a1.y + acc[5], 0.f);
        const float h6 = fmaxf(a1.z + acc[6], 0.f);
        const float h7 = fmaxf(a1.w + acc[7], 0.f);
        uint4 o;
        o.x = bf16pair(h0, h1);
        o.y = bf16pair(h2, h3);
        o.z = bf16pair(h4, h5);
        o.w = bf16pair(h6, h7);
        *(uint4*)(h16 + (size_t)n * HID + cl * 8) = o;
    }
}

// ---------------------------------------------------------------------------
// Kernel 4: MFMA decoder (proven). h (bf16) @ W_dec(->bf16) + b_dec -> f32.
// ---------------------------------------------------------------------------
__global__ __launch_bounds__(256) void graphmae_decode(
    const unsigned short* __restrict__ h16, const float* __restrict__ W_dec,
    const float* __restrict__ b_dec, float* __restrict__ out, int N)
{
    __shared__ unsigned short As[64][72];
    __shared__ unsigned short Bs[128][72];

    const int t  = threadIdx.x;
    const int n0 = blockIdx.x * 64;

    {
        const int r = t >> 2, q = t & 3;
        const int n = n0 + r;
        unsigned short* ap = &As[r][q * 16];
        if (n < N) {
            const unsigned short* hp = h16 + (size_t)n * HID + q * 16;
            #pragma unroll
            for (int j = 0; j < 4; ++j)
                *(uint2*)(ap + j * 4) = *(const uint2*)(hp + j * 4);
        } else {
            #pragma unroll
            for (int j = 0; j < 4; ++j) *(uint2*)(ap + j * 4) = make_uint2(0u, 0u);
        }
    }
    #pragma unroll
    for (int p = 0; p < 8; ++p) {
        const int idx = t + p * 256;
        const int k   = idx >> 5;
        const int c4  = (idx & 31) * 4;
        const float4 v = *(const float4*)(W_dec + (size_t)k * IN_CH + c4);
        Bs[c4 + 0][k] = bf16of(v.x);
        Bs[c4 + 1][k] = bf16of(v.y);
        Bs[c4 + 2][k] = bf16of(v.z);
        Bs[c4 + 3][k] = bf16of(v.w);
    }
    __syncthreads();

    const int w    = t >> 6;
    const int lane = t & 63;
    const int mr   = lane & 15;
    const int kg   = lane >> 4;

    v8s afrag[2];
    #pragma unroll
    for (int ks = 0; ks < 2; ++ks)
        afrag[ks] = *(const v8s*)(&As[w * 16 + mr][ks * 32 + kg * 8]);

    const int rbase = n0 + w * 16 + kg * 4;
    #pragma unroll
    for (int ct = 0; ct < 8; ++ct) {
        v4f acc = {0.f, 0.f, 0.f, 0.f};
        #pragma unroll
        for (int ks = 0; ks < 2; ++ks) {
            const v8s b = *(const v8s*)(&Bs[ct * 16 + mr][ks * 32 + kg * 8]);
            acc = __builtin_amdgcn_mfma_f32_16x16x32_bf16(afrag[ks], b, acc, 0, 0, 0);
        }
        const int c  = ct * 16 + mr;
        const float bd = b_dec[c];
        #pragma unroll
        for (int r = 0; r < 4; ++r) {
            const int n = rbase + r;
            if (n < N) out[(size_t)n * IN_CH + c] = acc[r] + bd;
        }
    }
}

// ---------------------------------------------------------------------------
extern "C" void kernel_launch(void* const* d_in, const int* in_sizes, int n_in,
                              void* d_out, int out_size, void* d_ws, size_t ws_size,
                              hipStream_t stream)
{
    const float* x      = (const float*)d_in[0];
    const int*   ei     = (const int*)  d_in[1];   // [2][E] int32
    const float* W_rel  = (const float*)d_in[2];
    const float* b_rel  = (const float*)d_in[3];
    const float* W_root = (const float*)d_in[4];
    const float* W_dec  = (const float*)d_in[5];
    const float* b_dec  = (const float*)d_in[6];
    float* out = (float*)d_out;

    const int N = in_sizes[0] / IN_CH;
    const int E = in_sizes[1] / 2;

    const int NBUK = (N + 255) / 256;      // 196 buckets (dst>>8)
    const int NPAD = NBUK * 256;           // 50176 padded node rows
    const int CE   = (E + NSCAT - 1) / NSCAT;

    unsigned short* y16 = (unsigned short*)d_ws;                   // [N][64] bf16
    float* agg          = (float*)(y16 + (size_t)N * HID);         // [N][64] f32
    unsigned short* h16 = (unsigned short*)(agg + (size_t)N * HID);// [N][64] bf16
    int* deg            = (int*)(h16 + (size_t)N * HID);           // [NPAD]
    unsigned short* slots16 = (unsigned short*)(deg + NPAD);       // [NPAD*ELLW]
    unsigned int* sorted = (unsigned int*)(slots16 + (size_t)NPAD * ELLW); // [NBUK*BCAP]
    int* bucketcur = (int*)(sorted + (size_t)NBUK * BCAP);         // [NBUK]
    int* spillcnt  = bucketcur + NBUK;                             // [1]+pad
    int2* spill    = (int2*)(spillcnt + 3);                        // [SPILLCAP]

    // zero bucketcur + spillcnt (contiguous, capture-safe)
    hipMemsetAsync(bucketcur, 0, (size_t)(NBUK + 1) * sizeof(int), stream);

    const int nblk64 = (N + 63) / 64;   // 782 blocks (>= NSCAT)

    graphmae_encode_scatter<<<nblk64, 512, 0, stream>>>(
        x, W_rel, b_rel, W_root, ei, y16, agg,
        bucketcur, sorted, spillcnt, spill, N, E, NBUK, CE);

    bucket_fill<<<NBUK, 256, 0, stream>>>(sorted, bucketcur, deg, slots16,
                                          spillcnt, spill);

    const int gblk = (N + 3) / 4;
    graphmae_gather<<<gblk, 256, 0, stream>>>(deg, slots16, y16, agg,
                                              spillcnt, spill, h16, N);
    graphmae_decode<<<nblk64, 256, 0, stream>>>(h16, W_dec, b_dec, out, N);
}

// Round 19
// 83.380 us; speedup vs baseline: 1.0958x; 1.0958x over previous
//
#include <hip/hip_runtime.h>

#define IN_CH 128
#define HID 64
#define ELLW 32        // 32 x ushort = 64B per node row
#define SPILLCAP 4096  // overflow edges (P ~ 0 for this graph)
#define NSCAT 256      // blocks carrying scatter duty
#define BCAP 3584      // fixed region capacity per 256-node bucket (mean 3061, +9 sigma)

typedef short v8s __attribute__((ext_vector_type(8)));   // 8 bf16 (4 VGPRs)
typedef float v4f __attribute__((ext_vector_type(4)));   // 4 f32 acc

// branch-free f32 -> bf16 (round-to-nearest-even), pure uint math
__device__ __forceinline__ unsigned int bf16pair(float a, float b) {
    unsigned int ua = __float_as_uint(a);
    unsigned int ub = __float_as_uint(b);
    ua = (ua + 0x7fffu + ((ua >> 16) & 1u)) >> 16;          // elem0 -> low 16
    ub = (ub + 0x7fffu + ((ub >> 16) & 1u)) & 0xffff0000u;  // elem1 -> high 16
    return ua | ub;
}
__device__ __forceinline__ unsigned short bf16of(float a) {
    unsigned int ua = __float_as_uint(a);
    return (unsigned short)((ua + 0x7fffu + ((ua >> 16) & 1u)) >> 16);
}

// ---------------------------------------------------------------------------
// Kernel 0: prep. Transpose [W_rel|W_root] (f32, [k][c]) -> Bt (bf16,
// [c][k], 32KB — L1-resident for the encode) with coalesced reads.
// Also zeroes bucketcur+spillcnt (replaces the memset dispatch).
// ---------------------------------------------------------------------------
__global__ __launch_bounds__(256) void graphmae_prep(
    const float* __restrict__ W_rel, const float* __restrict__ W_root,
    unsigned short* __restrict__ Bt, int* __restrict__ bucketcur, int NZ)
{
    const int idx = blockIdx.x * 256 + threadIdx.x;   // 0..16383
    if (idx < NZ) bucketcur[idx] = 0;
    const int k = idx >> 7;      // 0..127
    const int c = idx & 127;     // 0..127
    const float v = (c < HID) ? W_rel[(size_t)k * HID + c]
                              : W_root[(size_t)k * HID + (c - HID)];
    Bt[(size_t)c * 128 + k] = bf16of(v);
}

// ---------------------------------------------------------------------------
// Kernel 1: LDS-free MFMA encoder + co-resident bucket scatter.
// R18 post-mortem: the LDS transpose staging was a 16-way bank conflict
// (6.65M conflict cycles); MFMA itself was ~free. Fix: no GEMM LDS at all.
//   t<256 : A-fragments straight from x (k-contiguous, f32->bf16 in-reg,
//           proven (mr,kg) mapping); B-fragments straight from Bt (L1-hot).
//           32 MFMAs/wave; epilogue y16 (bf16) + agg (f32 + b_rel).
//   t>=256: blocks 0..NSCAT-1 — hist (overlaps MFMA); reserve; write.
// LDS = 2KB (lh/lcur only) -> high occupancy, no conflicts.
// ---------------------------------------------------------------------------
__global__ __launch_bounds__(512) void graphmae_encode_scatter(
    const float* __restrict__ x, const unsigned short* __restrict__ Bt,
    const float* __restrict__ b_rel, const int* __restrict__ ei,
    unsigned short* __restrict__ y16, float* __restrict__ agg,
    int* __restrict__ bucketcur, unsigned int* __restrict__ sorted,
    int* __restrict__ spillcnt, int2* __restrict__ spill,
    int N, int E, int NBUK, int CE)
{
    __shared__ int lh[256];    // scatter: per-bucket local count
    __shared__ int lcur[256];  // scatter: reserved base -> running cursor

    const int t  = threadIdx.x;
    const int n0 = blockIdx.x * 64;
    const bool sduty = (blockIdx.x < NSCAT);
    const int e0 = blockIdx.x * CE;
    const int e1 = sduty ? min(E, e0 + CE) : 0;

    if (t >= 256) { lh[t - 256] = 0; lcur[t - 256] = 0; }
    __syncthreads();   // B1: lh zeroed

    if (t < 256) {
        const int w    = t >> 6;
        const int lane = t & 63;
        const int mr   = lane & 15;
        const int kg   = lane >> 4;
        const int nrow = n0 + w * 16 + mr;

        v8s afrag[4];
        #pragma unroll
        for (int ks = 0; ks < 4; ++ks) {
            uint4 pk = make_uint4(0u, 0u, 0u, 0u);
            if (nrow < N) {
                const float* xp = x + (size_t)nrow * IN_CH + ks * 32 + kg * 8;
                const float4 u0 = *(const float4*)(xp);
                const float4 u1 = *(const float4*)(xp + 4);
                pk = make_uint4(bf16pair(u0.x, u0.y), bf16pair(u0.z, u0.w),
                                bf16pair(u1.x, u1.y), bf16pair(u1.z, u1.w));
            }
            afrag[ks] = *(v8s*)&pk;
        }

        const int rbase = n0 + w * 16 + kg * 4;   // C/D: row = kg*4 + reg
        #pragma unroll
        for (int ct = 0; ct < 8; ++ct) {
            v4f acc = {0.f, 0.f, 0.f, 0.f};
            const unsigned short* bp = Bt + (size_t)(ct * 16 + mr) * 128 + kg * 8;
            #pragma unroll
            for (int ks = 0; ks < 4; ++ks) {
                const v8s b = *(const v8s*)(bp + ks * 32);
                acc = __builtin_amdgcn_mfma_f32_16x16x32_bf16(afrag[ks], b, acc, 0, 0, 0);
            }
            const int c = ct * 16 + mr;           // C/D: col = lane&15
            if (ct < 4) {
                #pragma unroll
                for (int r = 0; r < 4; ++r) {
                    const int n = rbase + r;
                    if (n < N) y16[(size_t)n * HID + c] = bf16of(acc[r]);
                }
            } else {
                const float br = b_rel[c - HID];
                #pragma unroll
                for (int r = 0; r < 4; ++r) {
                    const int n = rbase + r;
                    if (n < N) agg[(size_t)n * HID + (c - HID)] = acc[r] + br;
                }
            }
        }
    } else if (sduty) {
        // ---- hist: LDS atomics over the block's edge chunk (overlaps MFMA) ----
        for (int e = e0 + (t - 256); e < e1; e += 256)
            atomicAdd(&lh[ei[E + e] >> 8], 1);
    }
    __syncthreads();   // B2: hist complete

    if (t >= 256 && sduty) {
        // ---- reserve: one returned global atomic per (block,bucket) ----
        const int b = t - 256;
        if (b < NBUK) {
            const int cnt = lh[b];
            if (cnt > 0) lcur[b] = atomicAdd(&bucketcur[b], cnt);
        }
    }
    __syncthreads();   // B3: cursors ready

    if (t >= 256 && sduty) {
        // ---- write: packed edges at LDS cursor positions ----
        for (int e = e0 + (t - 256); e < e1; e += 256) {
            const int d = ei[E + e];
            const int s = ei[e];
            const int b = d >> 8;
            const int pos = atomicAdd(&lcur[b], 1);
            if (pos < BCAP) {
                sorted[(size_t)b * BCAP + pos] =
                    ((unsigned)(d & 255) << 16) | (unsigned)s;
            } else {
                const int p = atomicAdd(spillcnt, 1);   // statistically never
                if (p < SPILLCAP) spill[p] = make_int2(d, s);
            }
        }
    }
}

// ---------------------------------------------------------------------------
// Kernel 2: per-bucket ELL fill, entirely in LDS; coalesced 16KB writeout.
// Writes deg for EVERY padded node (no pre-zero needed).
// ---------------------------------------------------------------------------
__global__ __launch_bounds__(256) void bucket_fill(
    const unsigned int* __restrict__ sorted, const int* __restrict__ bucketcur,
    int* __restrict__ deg, unsigned short* __restrict__ slots16,
    int* __restrict__ spillcnt, int2* __restrict__ spill)
{
    __shared__ int cnt[256];
    __shared__ unsigned short sl[256 * ELLW];   // 16KB
    const int t = threadIdx.x, b = blockIdx.x;
    cnt[t] = 0;
    __syncthreads();

    const int m = min(bucketcur[b], BCAP);
    const unsigned int* src = sorted + (size_t)b * BCAP;
    for (int i = t; i < m; i += 256) {
        const unsigned int v = src[i];
        const int dl = v >> 16;
        const int r = atomicAdd(&cnt[dl], 1);       // LDS atomic — fast
        if (r < ELLW) sl[dl * ELLW + r] = (unsigned short)(v & 0xffffu);
        else {
            const int p = atomicAdd(spillcnt, 1);   // statistically never
            if (p < SPILLCAP) spill[p] = make_int2((b << 8) + dl, (int)(v & 0xffffu));
        }
    }
    __syncthreads();

    deg[(b << 8) + t] = cnt[t];
    unsigned int* g = (unsigned int*)slots16 + (size_t)b * 4096;
    const unsigned int* l = (const unsigned int*)sl;
    for (int i = t; i < 4096; i += 256) g[i] = l[i];
}

// ---------------------------------------------------------------------------
// Kernel 3: gather (proven R10-R18 structure). One wave64 per node,
// 8 edge-slots x 8 col-lanes. h = relu(agg + sum) stored bf16.
// ---------------------------------------------------------------------------
__global__ __launch_bounds__(256) void graphmae_gather(
    const int* __restrict__ deg, const unsigned short* __restrict__ slots16,
    const unsigned short* __restrict__ y16, const float* __restrict__ agg,
    const int* __restrict__ spillcnt, const int2* __restrict__ spill,
    unsigned short* __restrict__ h16, int N)
{
    const int n = blockIdx.x * 4 + (threadIdx.x >> 6);
    if (n >= N) return;
    const int lane = threadIdx.x & 63;
    const int es   = lane >> 3;
    const int cl   = lane & 7;

    const int cnt = min(deg[n], ELLW);
    const unsigned short* sp = slots16 + (size_t)n * ELLW;

    float4 a0 = make_float4(0.f, 0.f, 0.f, 0.f);
    float4 a1 = make_float4(0.f, 0.f, 0.f, 0.f);
    if (es == 0) {
        a0 = *(const float4*)(agg + (size_t)n * HID + cl * 8);
        a1 = *(const float4*)(agg + (size_t)n * HID + cl * 8 + 4);
    }

    float acc[8];
    #pragma unroll
    for (int j = 0; j < 8; ++j) acc[j] = 0.f;

    for (int e = es; e < cnt; e += 8) {
        const int s = sp[e];
        const uint4 v = *(const uint4*)(y16 + (size_t)s * HID + cl * 8);
        acc[0] += __uint_as_float(v.x << 16);
        acc[1] += __uint_as_float(v.x & 0xffff0000u);
        acc[2] += __uint_as_float(v.y << 16);
        acc[3] += __uint_as_float(v.y & 0xffff0000u);
        acc[4] += __uint_as_float(v.z << 16);
        acc[5] += __uint_as_float(v.z & 0xffff0000u);
        acc[6] += __uint_as_float(v.w << 16);
        acc[7] += __uint_as_float(v.w & 0xffff0000u);
    }

    const int spN = min(*spillcnt, SPILLCAP);
    for (int i = es; i < spN; i += 8) {
        const int2 e2 = spill[i];
        if (e2.x == n) {
            const uint4 v = *(const uint4*)(y16 + (size_t)e2.y * HID + cl * 8);
            acc[0] += __uint_as_float(v.x << 16);
            acc[1] += __uint_as_float(v.x & 0xffff0000u);
            acc[2] += __uint_as_float(v.y << 16);
            acc[3] += __uint_as_float(v.y & 0xffff0000u);
            acc[4] += __uint_as_float(v.z << 16);
            acc[5] += __uint_as_float(v.z & 0xffff0000u);
            acc[6] += __uint_as_float(v.w << 16);
            acc[7] += __uint_as_float(v.w & 0xffff0000u);
        }
    }

    #pragma unroll
    for (int m = 8; m <= 32; m <<= 1) {
        #pragma unroll
        for (int j = 0; j < 8; ++j) acc[j] += __shfl_xor(acc[j], m);
    }

    if (es == 0) {
        const float h0 = fmaxf(a0.x + acc[0], 0.f);
        const float h1 = fmaxf(a0.y + acc[1], 0.f);
        const float h2 = fmaxf(a0.z + acc[2], 0.f);
        const float h3 = fmaxf(a0.w + acc[3], 0.f);
        const float h4 = fmaxf(a1.x + acc[4], 0.f);
        const float h5 = fmaxf(a1.y + acc[5], 0.f);
        const float h6 = fmaxf(a1.z + acc[6], 0.f);
        const float h7 = fmaxf(a1.w + acc[7], 0.f);
        uint4 o;
        o.x = bf16pair(h0, h1);
        o.y = bf16pair(h2, h3);
        o.z = bf16pair(h4, h5);
        o.w = bf16pair(h6, h7);
        *(uint4*)(h16 + (size_t)n * HID + cl * 8) = o;
    }
}

// ---------------------------------------------------------------------------
// Kernel 4: MFMA decoder (proven). h (bf16) @ W_dec(->bf16) + b_dec -> f32.
// ---------------------------------------------------------------------------
__global__ __launch_bounds__(256) void graphmae_decode(
    const unsigned short* __restrict__ h16, const float* __restrict__ W_dec,
    const float* __restrict__ b_dec, float* __restrict__ out, int N)
{
    __shared__ unsigned short As[64][72];
    __shared__ unsigned short Bs[128][72];

    const int t  = threadIdx.x;
    const int n0 = blockIdx.x * 64;

    {
        const int r = t >> 2, q = t & 3;
        const int n = n0 + r;
        unsigned short* ap = &As[r][q * 16];
        if (n < N) {
            const unsigned short* hp = h16 + (size_t)n * HID + q * 16;
            #pragma unroll
            for (int j = 0; j < 4; ++j)
                *(uint2*)(ap + j * 4) = *(const uint2*)(hp + j * 4);
        } else {
            #pragma unroll
            for (int j = 0; j < 4; ++j) *(uint2*)(ap + j * 4) = make_uint2(0u, 0u);
        }
    }
    #pragma unroll
    for (int p = 0; p < 8; ++p) {
        const int idx = t + p * 256;
        const int k   = idx >> 5;
        const int c4  = (idx & 31) * 4;
        const float4 v = *(const float4*)(W_dec + (size_t)k * IN_CH + c4);
        Bs[c4 + 0][k] = bf16of(v.x);
        Bs[c4 + 1][k] = bf16of(v.y);
        Bs[c4 + 2][k] = bf16of(v.z);
        Bs[c4 + 3][k] = bf16of(v.w);
    }
    __syncthreads();

    const int w    = t >> 6;
    const int lane = t & 63;
    const int mr   = lane & 15;
    const int kg   = lane >> 4;

    v8s afrag[2];
    #pragma unroll
    for (int ks = 0; ks < 2; ++ks)
        afrag[ks] = *(const v8s*)(&As[w * 16 + mr][ks * 32 + kg * 8]);

    const int rbase = n0 + w * 16 + kg * 4;
    #pragma unroll
    for (int ct = 0; ct < 8; ++ct) {
        v4f acc = {0.f, 0.f, 0.f, 0.f};
        #pragma unroll
        for (int ks = 0; ks < 2; ++ks) {
            const v8s b = *(const v8s*)(&Bs[ct * 16 + mr][ks * 32 + kg * 8]);
            acc = __builtin_amdgcn_mfma_f32_16x16x32_bf16(afrag[ks], b, acc, 0, 0, 0);
        }
        const int c  = ct * 16 + mr;
        const float bd = b_dec[c];
        #pragma unroll
        for (int r = 0; r < 4; ++r) {
            const int n = rbase + r;
            if (n < N) out[(size_t)n * IN_CH + c] = acc[r] + bd;
        }
    }
}

// ---------------------------------------------------------------------------
extern "C" void kernel_launch(void* const* d_in, const int* in_sizes, int n_in,
                              void* d_out, int out_size, void* d_ws, size_t ws_size,
                              hipStream_t stream)
{
    const float* x      = (const float*)d_in[0];
    const int*   ei     = (const int*)  d_in[1];   // [2][E] int32
    const float* W_rel  = (const float*)d_in[2];
    const float* b_rel  = (const float*)d_in[3];
    const float* W_root = (const float*)d_in[4];
    const float* W_dec  = (const float*)d_in[5];
    const float* b_dec  = (const float*)d_in[6];
    float* out = (float*)d_out;

    const int N = in_sizes[0] / IN_CH;
    const int E = in_sizes[1] / 2;

    const int NBUK = (N + 255) / 256;      // 196 buckets (dst>>8)
    const int NPAD = NBUK * 256;           // 50176 padded node rows
    const int CE   = (E + NSCAT - 1) / NSCAT;

    unsigned short* y16 = (unsigned short*)d_ws;                   // [N][64] bf16
    float* agg          = (float*)(y16 + (size_t)N * HID);         // [N][64] f32
    unsigned short* h16 = (unsigned short*)(agg + (size_t)N * HID);// [N][64] bf16
    int* deg            = (int*)(h16 + (size_t)N * HID);           // [NPAD]
    unsigned short* slots16 = (unsigned short*)(deg + NPAD);       // [NPAD*ELLW]
    unsigned int* sorted = (unsigned int*)(slots16 + (size_t)NPAD * ELLW); // [NBUK*BCAP]
    int* bucketcur = (int*)(sorted + (size_t)NBUK * BCAP);         // [NBUK]
    int* spillcnt  = bucketcur + NBUK;                             // [1]+pad
    int2* spill    = (int2*)(spillcnt + 3);                        // [SPILLCAP]
    unsigned short* Bt = (unsigned short*)(spill + SPILLCAP);      // [128*128] bf16

    const int nblk64 = (N + 63) / 64;   // 782 blocks (>= NSCAT)

    // prep: Bt transpose + zero bucketcur/spillcnt (NBUK+1 ints)
    graphmae_prep<<<64, 256, 0, stream>>>(W_rel, W_root, Bt, bucketcur, NBUK + 1);

    graphmae_encode_scatter<<<nblk64, 512, 0, stream>>>(
        x, Bt, b_rel, ei, y16, agg,
        bucketcur, sorted, spillcnt, spill, N, E, NBUK, CE);

    bucket_fill<<<NBUK, 256, 0, stream>>>(sorted, bucketcur, deg, slots16,
                                          spillcnt, spill);

    const int gblk = (N + 3) / 4;
    graphmae_gather<<<gblk, 256, 0, stream>>>(deg, slots16, y16, agg,
                                              spillcnt, spill, h16, N);
    graphmae_decode<<<nblk64, 256, 0, stream>>>(h16, W_dec, b_dec, out, N);
}

// Round 20
// 81.866 us; speedup vs baseline: 1.1161x; 1.0185x over previous
//
#include <hip/hip_runtime.h>

#define IN_CH 128
#define HID 64
#define ELLW 32        // 32 x ushort = 64B per node row
#define SPILLCAP 4096  // overflow edges (P ~ 0 for this graph)
#define NSCAT 256      // blocks carrying scatter duty
#define BCAP 3584      // fixed region capacity per 256-node bucket (mean 3061, +9 sigma)

typedef short v8s __attribute__((ext_vector_type(8)));   // 8 bf16 (4 VGPRs)
typedef float v4f __attribute__((ext_vector_type(4)));   // 4 f32 acc

// branch-free f32 -> bf16 (round-to-nearest-even), pure uint math
__device__ __forceinline__ unsigned int bf16pair(float a, float b) {
    unsigned int ua = __float_as_uint(a);
    unsigned int ub = __float_as_uint(b);
    ua = (ua + 0x7fffu + ((ua >> 16) & 1u)) >> 16;          // elem0 -> low 16
    ub = (ub + 0x7fffu + ((ub >> 16) & 1u)) & 0xffff0000u;  // elem1 -> high 16
    return ua | ub;
}
__device__ __forceinline__ unsigned short bf16of(float a) {
    unsigned int ua = __float_as_uint(a);
    return (unsigned short)((ua + 0x7fffu + ((ua >> 16) & 1u)) >> 16);
}

// ---------------------------------------------------------------------------
// Kernel 0: prep. Bt = [W_rel|W_root]^T (bf16 [c:128][k:128], 32KB) and
// Wdt = W_dec^T (bf16 [c:128][k:64], 16KB) — both L1/L2-resident for the
// LDS-free MFMA kernels. Also zeroes bucketcur+spillcnt.
// ---------------------------------------------------------------------------
__global__ __launch_bounds__(256) void graphmae_prep(
    const float* __restrict__ W_rel, const float* __restrict__ W_root,
    const float* __restrict__ W_dec,
    unsigned short* __restrict__ Bt, unsigned short* __restrict__ Wdt,
    int* __restrict__ bucketcur, int NZ)
{
    const int idx = blockIdx.x * 256 + threadIdx.x;   // 0..24575
    if (idx < NZ) bucketcur[idx] = 0;
    if (idx < 16384) {
        const int k = idx >> 7;      // 0..127
        const int c = idx & 127;     // 0..127
        const float v = (c < HID) ? W_rel[(size_t)k * HID + c]
                                  : W_root[(size_t)k * HID + (c - HID)];
        Bt[(size_t)c * 128 + k] = bf16of(v);
    } else if (idx < 24576) {
        const int j = idx - 16384;
        const int k = j >> 7;        // 0..63
        const int c = j & 127;       // 0..127
        Wdt[(size_t)c * 64 + k] = bf16of(W_dec[(size_t)k * IN_CH + c]);
    }
}

// ---------------------------------------------------------------------------
// Kernel 1: LDS-free MFMA encoder + co-resident bucket scatter.
// OPERAND-SWAPPED MFMA: mfma(Wfrag, xfrag) computes (x@W)^T in the standard
// C/D layout, so col=lane&15 indexes the NODE and the 4 acc regs are 4
// CONTIGUOUS output columns -> vector epilogue stores (uint2 y16 / float4
// agg) instead of R19's 2B/4B scalar scatter.
//   t<256 : MFMA (loads byte-identical to R19); t>=256: scatter duty.
// ---------------------------------------------------------------------------
__global__ __launch_bounds__(512) void graphmae_encode_scatter(
    const float* __restrict__ x, const unsigned short* __restrict__ Bt,
    const float* __restrict__ b_rel, const int* __restrict__ ei,
    unsigned short* __restrict__ y16, float* __restrict__ agg,
    int* __restrict__ bucketcur, unsigned int* __restrict__ sorted,
    int* __restrict__ spillcnt, int2* __restrict__ spill,
    int N, int E, int NBUK, int CE)
{
    __shared__ int lh[256];    // scatter: per-bucket local count
    __shared__ int lcur[256];  // scatter: reserved base -> running cursor

    const int t  = threadIdx.x;
    const int n0 = blockIdx.x * 64;
    const bool sduty = (blockIdx.x < NSCAT);
    const int e0 = blockIdx.x * CE;
    const int e1 = sduty ? min(E, e0 + CE) : 0;

    if (t >= 256) { lh[t - 256] = 0; lcur[t - 256] = 0; }
    __syncthreads();   // B1: lh zeroed

    if (t < 256) {
        const int w    = t >> 6;
        const int lane = t & 63;
        const int mr   = lane & 15;
        const int kg   = lane >> 4;
        const int nrow = n0 + w * 16 + mr;   // this lane's node (D col)

        v8s xfrag[4];
        #pragma unroll
        for (int ks = 0; ks < 4; ++ks) {
            uint4 pk = make_uint4(0u, 0u, 0u, 0u);
            if (nrow < N) {
                const float* xp = x + (size_t)nrow * IN_CH + ks * 32 + kg * 8;
                const float4 u0 = *(const float4*)(xp);
                const float4 u1 = *(const float4*)(xp + 4);
                pk = make_uint4(bf16pair(u0.x, u0.y), bf16pair(u0.z, u0.w),
                                bf16pair(u1.x, u1.y), bf16pair(u1.z, u1.w));
            }
            xfrag[ks] = *(v8s*)&pk;
        }

        #pragma unroll
        for (int ct = 0; ct < 8; ++ct) {
            v4f acc = {0.f, 0.f, 0.f, 0.f};
            const unsigned short* bp = Bt + (size_t)(ct * 16 + mr) * 128 + kg * 8;
            #pragma unroll
            for (int ks = 0; ks < 4; ++ks) {
                const v8s b = *(const v8s*)(bp + ks * 32);
                // swapped: A = W-fragment, B = x-fragment -> D = (x@W)^T
                acc = __builtin_amdgcn_mfma_f32_16x16x32_bf16(b, xfrag[ks], acc, 0, 0, 0);
            }
            if (nrow < N) {
                if (ct < 4) {
                    const int c = ct * 16 + kg * 4;   // contiguous y16 cols
                    *(uint2*)(y16 + (size_t)nrow * HID + c) =
                        make_uint2(bf16pair(acc[0], acc[1]), bf16pair(acc[2], acc[3]));
                } else {
                    const int c = (ct - 4) * 16 + kg * 4;
                    const float4 br = *(const float4*)(b_rel + c);
                    *(float4*)(agg + (size_t)nrow * HID + c) =
                        make_float4(acc[0] + br.x, acc[1] + br.y,
                                    acc[2] + br.z, acc[3] + br.w);
                }
            }
        }
    } else if (sduty) {
        // ---- hist: LDS atomics over the block's edge chunk (overlaps MFMA) ----
        for (int e = e0 + (t - 256); e < e1; e += 256)
            atomicAdd(&lh[ei[E + e] >> 8], 1);
    }
    __syncthreads();   // B2: hist complete

    if (t >= 256 && sduty) {
        const int b = t - 256;
        if (b < NBUK) {
            const int cnt = lh[b];
            if (cnt > 0) lcur[b] = atomicAdd(&bucketcur[b], cnt);
        }
    }
    __syncthreads();   // B3: cursors ready

    if (t >= 256 && sduty) {
        for (int e = e0 + (t - 256); e < e1; e += 256) {
            const int d = ei[E + e];
            const int s = ei[e];
            const int b = d >> 8;
            const int pos = atomicAdd(&lcur[b], 1);
            if (pos < BCAP) {
                sorted[(size_t)b * BCAP + pos] =
                    ((unsigned)(d & 255) << 16) | (unsigned)s;
            } else {
                const int p = atomicAdd(spillcnt, 1);   // statistically never
                if (p < SPILLCAP) spill[p] = make_int2(d, s);
            }
        }
    }
}

// ---------------------------------------------------------------------------
// Kernel 2: per-bucket ELL fill, entirely in LDS; coalesced 16KB writeout.
// ---------------------------------------------------------------------------
__global__ __launch_bounds__(256) void bucket_fill(
    const unsigned int* __restrict__ sorted, const int* __restrict__ bucketcur,
    int* __restrict__ deg, unsigned short* __restrict__ slots16,
    int* __restrict__ spillcnt, int2* __restrict__ spill)
{
    __shared__ int cnt[256];
    __shared__ unsigned short sl[256 * ELLW];   // 16KB
    const int t = threadIdx.x, b = blockIdx.x;
    cnt[t] = 0;
    __syncthreads();

    const int m = min(bucketcur[b], BCAP);
    const unsigned int* src = sorted + (size_t)b * BCAP;
    for (int i = t; i < m; i += 256) {
        const unsigned int v = src[i];
        const int dl = v >> 16;
        const int r = atomicAdd(&cnt[dl], 1);       // LDS atomic — fast
        if (r < ELLW) sl[dl * ELLW + r] = (unsigned short)(v & 0xffffu);
        else {
            const int p = atomicAdd(spillcnt, 1);   // statistically never
            if (p < SPILLCAP) spill[p] = make_int2((b << 8) + dl, (int)(v & 0xffffu));
        }
    }
    __syncthreads();

    deg[(b << 8) + t] = cnt[t];
    unsigned int* g = (unsigned int*)slots16 + (size_t)b * 4096;
    const unsigned int* l = (const unsigned int*)sl;
    for (int i = t; i < 4096; i += 256) g[i] = l[i];
}

// ---------------------------------------------------------------------------
// Kernel 3: gather (proven R10-R19 structure). One wave64 per node,
// 8 edge-slots x 8 col-lanes. h = relu(agg + sum) stored bf16.
// ---------------------------------------------------------------------------
__global__ __launch_bounds__(256) void graphmae_gather(
    const int* __restrict__ deg, const unsigned short* __restrict__ slots16,
    const unsigned short* __restrict__ y16, const float* __restrict__ agg,
    const int* __restrict__ spillcnt, const int2* __restrict__ spill,
    unsigned short* __restrict__ h16, int N)
{
    const int n = blockIdx.x * 4 + (threadIdx.x >> 6);
    if (n >= N) return;
    const int lane = threadIdx.x & 63;
    const int es   = lane >> 3;
    const int cl   = lane & 7;

    const int cnt = min(deg[n], ELLW);
    const unsigned short* sp = slots16 + (size_t)n * ELLW;

    float4 a0 = make_float4(0.f, 0.f, 0.f, 0.f);
    float4 a1 = make_float4(0.f, 0.f, 0.f, 0.f);
    if (es == 0) {
        a0 = *(const float4*)(agg + (size_t)n * HID + cl * 8);
        a1 = *(const float4*)(agg + (size_t)n * HID + cl * 8 + 4);
    }

    float acc[8];
    #pragma unroll
    for (int j = 0; j < 8; ++j) acc[j] = 0.f;

    for (int e = es; e < cnt; e += 8) {
        const int s = sp[e];
        const uint4 v = *(const uint4*)(y16 + (size_t)s * HID + cl * 8);
        acc[0] += __uint_as_float(v.x << 16);
        acc[1] += __uint_as_float(v.x & 0xffff0000u);
        acc[2] += __uint_as_float(v.y << 16);
        acc[3] += __uint_as_float(v.y & 0xffff0000u);
        acc[4] += __uint_as_float(v.z << 16);
        acc[5] += __uint_as_float(v.z & 0xffff0000u);
        acc[6] += __uint_as_float(v.w << 16);
        acc[7] += __uint_as_float(v.w & 0xffff0000u);
    }

    const int spN = min(*spillcnt, SPILLCAP);
    for (int i = es; i < spN; i += 8) {
        const int2 e2 = spill[i];
        if (e2.x == n) {
            const uint4 v = *(const uint4*)(y16 + (size_t)e2.y * HID + cl * 8);
            acc[0] += __uint_as_float(v.x << 16);
            acc[1] += __uint_as_float(v.x & 0xffff0000u);
            acc[2] += __uint_as_float(v.y << 16);
            acc[3] += __uint_as_float(v.y & 0xffff0000u);
            acc[4] += __uint_as_float(v.z << 16);
            acc[5] += __uint_as_float(v.z & 0xffff0000u);
            acc[6] += __uint_as_float(v.w << 16);
            acc[7] += __uint_as_float(v.w & 0xffff0000u);
        }
    }

    #pragma unroll
    for (int m = 8; m <= 32; m <<= 1) {
        #pragma unroll
        for (int j = 0; j < 8; ++j) acc[j] += __shfl_xor(acc[j], m);
    }

    if (es == 0) {
        const float h0 = fmaxf(a0.x + acc[0], 0.f);
        const float h1 = fmaxf(a0.y + acc[1], 0.f);
        const float h2 = fmaxf(a0.z + acc[2], 0.f);
        const float h3 = fmaxf(a0.w + acc[3], 0.f);
        const float h4 = fmaxf(a1.x + acc[4], 0.f);
        const float h5 = fmaxf(a1.y + acc[5], 0.f);
        const float h6 = fmaxf(a1.z + acc[6], 0.f);
        const float h7 = fmaxf(a1.w + acc[7], 0.f);
        uint4 o;
        o.x = bf16pair(h0, h1);
        o.y = bf16pair(h2, h3);
        o.z = bf16pair(h4, h5);
        o.w = bf16pair(h6, h7);
        *(uint4*)(h16 + (size_t)n * HID + cl * 8) = o;
    }
}

// ---------------------------------------------------------------------------
// Kernel 4: LDS-free MFMA decoder, operand-swapped.
// hfrag straight from h16 (lane's own node row, 16B loads); Wd-fragments
// from Wdt (L1-hot). D = (h@W_dec)^T layout -> lane owns node nrow and 4
// contiguous out cols per ct -> float4 stores. No LDS, no barrier.
// ---------------------------------------------------------------------------
__global__ __launch_bounds__(256) void graphmae_decode(
    const unsigned short* __restrict__ h16, const unsigned short* __restrict__ Wdt,
    const float* __restrict__ b_dec, float* __restrict__ out, int N)
{
    const int t  = threadIdx.x;
    const int n0 = blockIdx.x * 64;
    const int w    = t >> 6;
    const int lane = t & 63;
    const int mr   = lane & 15;
    const int kg   = lane >> 4;
    const int nrow = n0 + w * 16 + mr;

    v8s hfrag[2];
    #pragma unroll
    for (int ks = 0; ks < 2; ++ks) {
        uint4 pk = make_uint4(0u, 0u, 0u, 0u);
        if (nrow < N)
            pk = *(const uint4*)(h16 + (size_t)nrow * HID + ks * 32 + kg * 8);
        hfrag[ks] = *(v8s*)&pk;
    }

    #pragma unroll
    for (int ct = 0; ct < 8; ++ct) {
        v4f acc = {0.f, 0.f, 0.f, 0.f};
        const unsigned short* wp = Wdt + (size_t)(ct * 16 + mr) * 64 + kg * 8;
        #pragma unroll
        for (int ks = 0; ks < 2; ++ks) {
            const v8s b = *(const v8s*)(wp + ks * 32);
            acc = __builtin_amdgcn_mfma_f32_16x16x32_bf16(b, hfrag[ks], acc, 0, 0, 0);
        }
        if (nrow < N) {
            const int c = ct * 16 + kg * 4;
            const float4 bd = *(const float4*)(b_dec + c);
            *(float4*)(out + (size_t)nrow * IN_CH + c) =
                make_float4(acc[0] + bd.x, acc[1] + bd.y,
                            acc[2] + bd.z, acc[3] + bd.w);
        }
    }
}

// ---------------------------------------------------------------------------
extern "C" void kernel_launch(void* const* d_in, const int* in_sizes, int n_in,
                              void* d_out, int out_size, void* d_ws, size_t ws_size,
                              hipStream_t stream)
{
    const float* x      = (const float*)d_in[0];
    const int*   ei     = (const int*)  d_in[1];   // [2][E] int32
    const float* W_rel  = (const float*)d_in[2];
    const float* b_rel  = (const float*)d_in[3];
    const float* W_root = (const float*)d_in[4];
    const float* W_dec  = (const float*)d_in[5];
    const float* b_dec  = (const float*)d_in[6];
    float* out = (float*)d_out;

    const int N = in_sizes[0] / IN_CH;
    const int E = in_sizes[1] / 2;

    const int NBUK = (N + 255) / 256;      // 196 buckets (dst>>8)
    const int NPAD = NBUK * 256;           // 50176 padded node rows
    const int CE   = (E + NSCAT - 1) / NSCAT;

    unsigned short* y16 = (unsigned short*)d_ws;                   // [N][64] bf16
    float* agg          = (float*)(y16 + (size_t)N * HID);         // [N][64] f32
    unsigned short* h16 = (unsigned short*)(agg + (size_t)N * HID);// [N][64] bf16
    int* deg            = (int*)(h16 + (size_t)N * HID);           // [NPAD]
    unsigned short* slots16 = (unsigned short*)(deg + NPAD);       // [NPAD*ELLW]
    unsigned int* sorted = (unsigned int*)(slots16 + (size_t)NPAD * ELLW); // [NBUK*BCAP]
    int* bucketcur = (int*)(sorted + (size_t)NBUK * BCAP);         // [NBUK]
    int* spillcnt  = bucketcur + NBUK;                             // [1]+pad
    int2* spill    = (int2*)(spillcnt + 3);                        // [SPILLCAP]
    unsigned short* Bt  = (unsigned short*)(spill + SPILLCAP);     // [128*128] bf16
    unsigned short* Wdt = Bt + 128 * 128;                          // [128*64] bf16

    const int nblk64 = (N + 63) / 64;   // 782 blocks (>= NSCAT)

    // prep: Bt + Wdt transposes + zero bucketcur/spillcnt (NBUK+1 ints)
    graphmae_prep<<<96, 256, 0, stream>>>(W_rel, W_root, W_dec, Bt, Wdt,
                                          bucketcur, NBUK + 1);

    graphmae_encode_scatter<<<nblk64, 512, 0, stream>>>(
        x, Bt, b_rel, ei, y16, agg,
        bucketcur, sorted, spillcnt, spill, N, E, NBUK, CE);

    bucket_fill<<<NBUK, 256, 0, stream>>>(sorted, bucketcur, deg, slots16,
                                          spillcnt, spill);

    const int gblk = (N + 3) / 4;
    graphmae_gather<<<gblk, 256, 0, stream>>>(deg, slots16, y16, agg,
                                              spillcnt, spill, h16, N);
    graphmae_decode<<<nblk64, 256, 0, stream>>>(h16, Wdt, b_dec, out, N);
}

// Round 21
// 80.161 us; speedup vs baseline: 1.1398x; 1.0213x over previous
//
#include <hip/hip_runtime.h>

#define IN_CH 128
#define HID 64
#define ELLW 32        // 32 slots per node row (in LDS)
#define SPILLCAP 4096  // global overflow edges (BCAP overflow; P ~ 0)
#define LSPCAP 128     // block-local ELL-overflow edges (deg>32; P ~ 2e-3 graph-wide)
#define NSCAT 256      // blocks carrying scatter duty
#define BCAP 3584      // fixed region capacity per 256-node bucket (mean 3061, +9 sigma)

typedef short v8s __attribute__((ext_vector_type(8)));   // 8 bf16 (4 VGPRs)
typedef float v4f __attribute__((ext_vector_type(4)));   // 4 f32 acc

// branch-free f32 -> bf16 (round-to-nearest-even), pure uint math
__device__ __forceinline__ unsigned int bf16pair(float a, float b) {
    unsigned int ua = __float_as_uint(a);
    unsigned int ub = __float_as_uint(b);
    ua = (ua + 0x7fffu + ((ua >> 16) & 1u)) >> 16;          // elem0 -> low 16
    ub = (ub + 0x7fffu + ((ub >> 16) & 1u)) & 0xffff0000u;  // elem1 -> high 16
    return ua | ub;
}
__device__ __forceinline__ unsigned short bf16of(float a) {
    unsigned int ua = __float_as_uint(a);
    return (unsigned short)((ua + 0x7fffu + ((ua >> 16) & 1u)) >> 16);
}

// ---------------------------------------------------------------------------
// Kernel 0: prep. Bt = [W_rel|W_root]^T (bf16 [c:128][k:128], 32KB) and
// Wdt = W_dec^T (bf16 [c:128][k:64], 16KB). Zeroes bucketcur+spillcnt.
// ---------------------------------------------------------------------------
__global__ __launch_bounds__(256) void graphmae_prep(
    const float* __restrict__ W_rel, const float* __restrict__ W_root,
    const float* __restrict__ W_dec,
    unsigned short* __restrict__ Bt, unsigned short* __restrict__ Wdt,
    int* __restrict__ bucketcur, int NZ)
{
    const int idx = blockIdx.x * 256 + threadIdx.x;   // 0..24575
    if (idx < NZ) bucketcur[idx] = 0;
    if (idx < 16384) {
        const int k = idx >> 7;      // 0..127
        const int c = idx & 127;     // 0..127
        const float v = (c < HID) ? W_rel[(size_t)k * HID + c]
                                  : W_root[(size_t)k * HID + (c - HID)];
        Bt[(size_t)c * 128 + k] = bf16of(v);
    } else if (idx < 24576) {
        const int j = idx - 16384;
        const int k = j >> 7;        // 0..63
        const int c = j & 127;       // 0..127
        Wdt[(size_t)c * 64 + k] = bf16of(W_dec[(size_t)k * IN_CH + c]);
    }
}

// ---------------------------------------------------------------------------
// Kernel 1: LDS-free MFMA encoder + co-resident bucket scatter (R20 proven).
// Operand-swapped MFMA -> D=(x@W)^T -> lane owns one node, 4 contiguous
// output cols per ct -> vector epilogue stores.
// ---------------------------------------------------------------------------
__global__ __launch_bounds__(512) void graphmae_encode_scatter(
    const float* __restrict__ x, const unsigned short* __restrict__ Bt,
    const float* __restrict__ b_rel, const int* __restrict__ ei,
    unsigned short* __restrict__ y16, float* __restrict__ agg,
    int* __restrict__ bucketcur, unsigned int* __restrict__ sorted,
    int* __restrict__ spillcnt, int2* __restrict__ spill,
    int N, int E, int NBUK, int CE)
{
    __shared__ int lh[256];    // scatter: per-bucket local count
    __shared__ int lcur[256];  // scatter: reserved base -> running cursor

    const int t  = threadIdx.x;
    const int n0 = blockIdx.x * 64;
    const bool sduty = (blockIdx.x < NSCAT);
    const int e0 = blockIdx.x * CE;
    const int e1 = sduty ? min(E, e0 + CE) : 0;

    if (t >= 256) { lh[t - 256] = 0; lcur[t - 256] = 0; }
    __syncthreads();   // B1: lh zeroed

    if (t < 256) {
        const int w    = t >> 6;
        const int lane = t & 63;
        const int mr   = lane & 15;
        const int kg   = lane >> 4;
        const int nrow = n0 + w * 16 + mr;   // this lane's node (D col)

        v8s xfrag[4];
        #pragma unroll
        for (int ks = 0; ks < 4; ++ks) {
            uint4 pk = make_uint4(0u, 0u, 0u, 0u);
            if (nrow < N) {
                const float* xp = x + (size_t)nrow * IN_CH + ks * 32 + kg * 8;
                const float4 u0 = *(const float4*)(xp);
                const float4 u1 = *(const float4*)(xp + 4);
                pk = make_uint4(bf16pair(u0.x, u0.y), bf16pair(u0.z, u0.w),
                                bf16pair(u1.x, u1.y), bf16pair(u1.z, u1.w));
            }
            xfrag[ks] = *(v8s*)&pk;
        }

        #pragma unroll
        for (int ct = 0; ct < 8; ++ct) {
            v4f acc = {0.f, 0.f, 0.f, 0.f};
            const unsigned short* bp = Bt + (size_t)(ct * 16 + mr) * 128 + kg * 8;
            #pragma unroll
            for (int ks = 0; ks < 4; ++ks) {
                const v8s b = *(const v8s*)(bp + ks * 32);
                acc = __builtin_amdgcn_mfma_f32_16x16x32_bf16(b, xfrag[ks], acc, 0, 0, 0);
            }
            if (nrow < N) {
                if (ct < 4) {
                    const int c = ct * 16 + kg * 4;
                    *(uint2*)(y16 + (size_t)nrow * HID + c) =
                        make_uint2(bf16pair(acc[0], acc[1]), bf16pair(acc[2], acc[3]));
                } else {
                    const int c = (ct - 4) * 16 + kg * 4;
                    const float4 br = *(const float4*)(b_rel + c);
                    *(float4*)(agg + (size_t)nrow * HID + c) =
                        make_float4(acc[0] + br.x, acc[1] + br.y,
                                    acc[2] + br.z, acc[3] + br.w);
                }
            }
        }
    } else if (sduty) {
        for (int e = e0 + (t - 256); e < e1; e += 256)
            atomicAdd(&lh[ei[E + e] >> 8], 1);
    }
    __syncthreads();   // B2: hist complete

    if (t >= 256 && sduty) {
        const int b = t - 256;
        if (b < NBUK) {
            const int cnt = lh[b];
            if (cnt > 0) lcur[b] = atomicAdd(&bucketcur[b], cnt);
        }
    }
    __syncthreads();   // B3: cursors ready

    if (t >= 256 && sduty) {
        for (int e = e0 + (t - 256); e < e1; e += 256) {
            const int d = ei[E + e];
            const int s = ei[e];
            const int b = d >> 8;
            const int pos = atomicAdd(&lcur[b], 1);
            if (pos < BCAP) {
                sorted[(size_t)b * BCAP + pos] =
                    ((unsigned)(d & 255) << 16) | (unsigned)s;
            } else {
                const int p = atomicAdd(spillcnt, 1);   // statistically never
                if (p < SPILLCAP) spill[p] = make_int2(d, s);
            }
        }
    }
}

// ---------------------------------------------------------------------------
// Kernel 2: FUSED bucket-fill + gather. Grid = NBUK x 8; block (b, split)
// owns 32 nodes. Phase 1: scan bucket b's sorted segment, build ELL rows
// for own nodes in LDS (2KB); deg>ELLW goes to a block-LOCAL spill (no
// cross-block race — the overflowing node belongs to THIS block). Phase 2:
// 4 waves x 8 nodes, proven 8-es x 8-cl gather from LDS slot lists.
// Kills slots16/deg round-trips and one dispatch.
// ---------------------------------------------------------------------------
__global__ __launch_bounds__(256) void bucket_gather(
    const unsigned int* __restrict__ sorted, const int* __restrict__ bucketcur,
    const unsigned short* __restrict__ y16, const float* __restrict__ agg,
    const int* __restrict__ spillcnt, const int2* __restrict__ spill,
    unsigned short* __restrict__ h16, int N)
{
    __shared__ unsigned short sl[32 * ELLW];   // 2KB slot lists
    __shared__ int cnt[32];
    __shared__ int lsp[LSPCAP];                // local overflow: (dl<<16)|s
    __shared__ int lspcnt;

    const int t   = threadIdx.x;
    const int b   = blockIdx.x >> 3;     // bucket
    const int spl = blockIdx.x & 7;      // split
    const int dlo = spl * 32;            // own local-dst range [dlo, dlo+32)

    if (t < 32) cnt[t] = 0;
    if (t == 32) lspcnt = 0;
    __syncthreads();

    // ---- phase 1: scan bucket segment, keep own nodes ----
    const int m = min(bucketcur[b], BCAP);
    const unsigned int* src = sorted + (size_t)b * BCAP;
    for (int i = t; i < m; i += 256) {
        const unsigned int v = src[i];
        const int dl = (int)(v >> 16) - dlo;
        if ((unsigned)dl < 32u) {
            const int r = atomicAdd(&cnt[dl], 1);
            if (r < ELLW) {
                sl[dl * ELLW + r] = (unsigned short)(v & 0xffffu);
            } else {
                const int p = atomicAdd(&lspcnt, 1);   // P ~ 2e-3 graph-wide
                if (p < LSPCAP) lsp[p] = (dl << 16) | (int)(v & 0xffffu);
            }
        }
    }
    __syncthreads();

    // ---- phase 2: 4 waves x 8 nodes, gather ----
    const int wid  = t >> 6;
    const int lane = t & 63;
    const int es   = lane >> 3;   // edge slot 0..7
    const int cl   = lane & 7;    // col group: cols cl*8 .. cl*8+7
    const int lspN = min(lspcnt, LSPCAP);
    const int spN  = min(*spillcnt, SPILLCAP);

    for (int j = 0; j < 8; ++j) {
        const int dl = wid * 8 + j;          // local node 0..31
        const int n  = (b << 8) + dlo + dl;
        if (n >= N) continue;                // wave-uniform
        const int c_ = min(cnt[dl], ELLW);
        const unsigned short* sp = sl + dl * ELLW;

        float4 a0 = make_float4(0.f, 0.f, 0.f, 0.f);
        float4 a1 = make_float4(0.f, 0.f, 0.f, 0.f);
        if (es == 0) {
            a0 = *(const float4*)(agg + (size_t)n * HID + cl * 8);
            a1 = *(const float4*)(agg + (size_t)n * HID + cl * 8 + 4);
        }

        float acc[8];
        #pragma unroll
        for (int q = 0; q < 8; ++q) acc[q] = 0.f;

        for (int e = es; e < c_; e += 8) {
            const int s = sp[e];
            const uint4 v = *(const uint4*)(y16 + (size_t)s * HID + cl * 8);
            acc[0] += __uint_as_float(v.x << 16);
            acc[1] += __uint_as_float(v.x & 0xffff0000u);
            acc[2] += __uint_as_float(v.y << 16);
            acc[3] += __uint_as_float(v.y & 0xffff0000u);
            acc[4] += __uint_as_float(v.z << 16);
            acc[5] += __uint_as_float(v.z & 0xffff0000u);
            acc[6] += __uint_as_float(v.w << 16);
            acc[7] += __uint_as_float(v.w & 0xffff0000u);
        }
        // block-local ELL overflow (normally empty)
        for (int i = es; i < lspN; i += 8) {
            const int e2 = lsp[i];
            if ((e2 >> 16) == dl) {
                const int s = e2 & 0xffff;
                const uint4 v = *(const uint4*)(y16 + (size_t)s * HID + cl * 8);
                acc[0] += __uint_as_float(v.x << 16);
                acc[1] += __uint_as_float(v.x & 0xffff0000u);
                acc[2] += __uint_as_float(v.y << 16);
                acc[3] += __uint_as_float(v.y & 0xffff0000u);
                acc[4] += __uint_as_float(v.z << 16);
                acc[5] += __uint_as_float(v.z & 0xffff0000u);
                acc[6] += __uint_as_float(v.w << 16);
                acc[7] += __uint_as_float(v.w & 0xffff0000u);
            }
        }
        // global BCAP-overflow spill (normally empty)
        for (int i = es; i < spN; i += 8) {
            const int2 e2 = spill[i];
            if (e2.x == n) {
                const uint4 v = *(const uint4*)(y16 + (size_t)e2.y * HID + cl * 8);
                acc[0] += __uint_as_float(v.x << 16);
                acc[1] += __uint_as_float(v.x & 0xffff0000u);
                acc[2] += __uint_as_float(v.y << 16);
                acc[3] += __uint_as_float(v.y & 0xffff0000u);
                acc[4] += __uint_as_float(v.z << 16);
                acc[5] += __uint_as_float(v.z & 0xffff0000u);
                acc[6] += __uint_as_float(v.w << 16);
                acc[7] += __uint_as_float(v.w & 0xffff0000u);
            }
        }

        #pragma unroll
        for (int mk = 8; mk <= 32; mk <<= 1) {
            #pragma unroll
            for (int q = 0; q < 8; ++q) acc[q] += __shfl_xor(acc[q], mk);
        }

        if (es == 0) {
            const float h0 = fmaxf(a0.x + acc[0], 0.f);
            const float h1 = fmaxf(a0.y + acc[1], 0.f);
            const float h2 = fmaxf(a0.z + acc[2], 0.f);
            const float h3 = fmaxf(a0.w + acc[3], 0.f);
            const float h4 = fmaxf(a1.x + acc[4], 0.f);
            const float h5 = fmaxf(a1.y + acc[5], 0.f);
            const float h6 = fmaxf(a1.z + acc[6], 0.f);
            const float h7 = fmaxf(a1.w + acc[7], 0.f);
            uint4 o;
            o.x = bf16pair(h0, h1);
            o.y = bf16pair(h2, h3);
            o.z = bf16pair(h4, h5);
            o.w = bf16pair(h6, h7);
            *(uint4*)(h16 + (size_t)n * HID + cl * 8) = o;
        }
    }
}

// ---------------------------------------------------------------------------
// Kernel 3: LDS-free MFMA decoder, operand-swapped (R20 proven).
// ---------------------------------------------------------------------------
__global__ __launch_bounds__(256) void graphmae_decode(
    const unsigned short* __restrict__ h16, const unsigned short* __restrict__ Wdt,
    const float* __restrict__ b_dec, float* __restrict__ out, int N)
{
    const int t  = threadIdx.x;
    const int n0 = blockIdx.x * 64;
    const int w    = t >> 6;
    const int lane = t & 63;
    const int mr   = lane & 15;
    const int kg   = lane >> 4;
    const int nrow = n0 + w * 16 + mr;

    v8s hfrag[2];
    #pragma unroll
    for (int ks = 0; ks < 2; ++ks) {
        uint4 pk = make_uint4(0u, 0u, 0u, 0u);
        if (nrow < N)
            pk = *(const uint4*)(h16 + (size_t)nrow * HID + ks * 32 + kg * 8);
        hfrag[ks] = *(v8s*)&pk;
    }

    #pragma unroll
    for (int ct = 0; ct < 8; ++ct) {
        v4f acc = {0.f, 0.f, 0.f, 0.f};
        const unsigned short* wp = Wdt + (size_t)(ct * 16 + mr) * 64 + kg * 8;
        #pragma unroll
        for (int ks = 0; ks < 2; ++ks) {
            const v8s b = *(const v8s*)(wp + ks * 32);
            acc = __builtin_amdgcn_mfma_f32_16x16x32_bf16(b, hfrag[ks], acc, 0, 0, 0);
        }
        if (nrow < N) {
            const int c = ct * 16 + kg * 4;
            const float4 bd = *(const float4*)(b_dec + c);
            *(float4*)(out + (size_t)nrow * IN_CH + c) =
                make_float4(acc[0] + bd.x, acc[1] + bd.y,
                            acc[2] + bd.z, acc[3] + bd.w);
        }
    }
}

// ---------------------------------------------------------------------------
extern "C" void kernel_launch(void* const* d_in, const int* in_sizes, int n_in,
                              void* d_out, int out_size, void* d_ws, size_t ws_size,
                              hipStream_t stream)
{
    const float* x      = (const float*)d_in[0];
    const int*   ei     = (const int*)  d_in[1];   // [2][E] int32
    const float* W_rel  = (const float*)d_in[2];
    const float* b_rel  = (const float*)d_in[3];
    const float* W_root = (const float*)d_in[4];
    const float* W_dec  = (const float*)d_in[5];
    const float* b_dec  = (const float*)d_in[6];
    float* out = (float*)d_out;

    const int N = in_sizes[0] / IN_CH;
    const int E = in_sizes[1] / 2;

    const int NBUK = (N + 255) / 256;      // 196 buckets (dst>>8)
    const int CE   = (E + NSCAT - 1) / NSCAT;

    unsigned short* y16 = (unsigned short*)d_ws;                   // [N][64] bf16
    float* agg          = (float*)(y16 + (size_t)N * HID);         // [N][64] f32
    unsigned short* h16 = (unsigned short*)(agg + (size_t)N * HID);// [N][64] bf16
    unsigned int* sorted = (unsigned int*)(h16 + (size_t)N * HID); // [NBUK*BCAP]
    int* bucketcur = (int*)(sorted + (size_t)NBUK * BCAP);         // [NBUK]
    int* spillcnt  = bucketcur + NBUK;                             // [1]+pad
    int2* spill    = (int2*)(spillcnt + 3);                        // [SPILLCAP]
    unsigned short* Bt  = (unsigned short*)(spill + SPILLCAP);     // [128*128] bf16
    unsigned short* Wdt = Bt + 128 * 128;                          // [128*64] bf16

    const int nblk64 = (N + 63) / 64;   // 782 blocks (>= NSCAT)

    graphmae_prep<<<96, 256, 0, stream>>>(W_rel, W_root, W_dec, Bt, Wdt,
                                          bucketcur, NBUK + 1);

    graphmae_encode_scatter<<<nblk64, 512, 0, stream>>>(
        x, Bt, b_rel, ei, y16, agg,
        bucketcur, sorted, spillcnt, spill, N, E, NBUK, CE);

    bucket_gather<<<NBUK * 8, 256, 0, stream>>>(sorted, bucketcur, y16, agg,
                                                spillcnt, spill, h16, N);

    graphmae_decode<<<nblk64, 256, 0, stream>>>(h16, Wdt, b_dec, out, N);
}

// Round 22
// 71.509 us; speedup vs baseline: 1.2777x; 1.1210x over previous
//
#include <hip/hip_runtime.h>

#define IN_CH 128
#define HID 64
#define ELLW 32        // 32 slots per node row (in LDS)
#define SPILLCAP 4096  // global overflow edges (BCAP overflow; P ~ 0)
#define LSPCAP 128     // block-local ELL-overflow edges (deg>32)
#define NSCAT 256      // blocks carrying scatter duty
#define BCAP 3584      // fixed region capacity per 256-node bucket (mean 3061, +9 sigma)

typedef short v8s __attribute__((ext_vector_type(8)));   // 8 bf16 (4 VGPRs)
typedef float v4f __attribute__((ext_vector_type(4)));   // 4 f32 acc

// branch-free f32 -> bf16 (round-to-nearest-even), pure uint math
__device__ __forceinline__ unsigned int bf16pair(float a, float b) {
    unsigned int ua = __float_as_uint(a);
    unsigned int ub = __float_as_uint(b);
    ua = (ua + 0x7fffu + ((ua >> 16) & 1u)) >> 16;          // elem0 -> low 16
    ub = (ub + 0x7fffu + ((ub >> 16) & 1u)) & 0xffff0000u;  // elem1 -> high 16
    return ua | ub;
}
__device__ __forceinline__ unsigned short bf16of(float a) {
    unsigned int ua = __float_as_uint(a);
    return (unsigned short)((ua + 0x7fffu + ((ua >> 16) & 1u)) >> 16);
}

// ---------------------------------------------------------------------------
// Kernel 0: prep. Bt = [W_rel|W_root]^T (bf16 [c:128][k:128], 32KB) and
// Wdt = W_dec^T (bf16 [c:128][k:64], 16KB). Zeroes bucketcur+spillcnt.
// ---------------------------------------------------------------------------
__global__ __launch_bounds__(256) void graphmae_prep(
    const float* __restrict__ W_rel, const float* __restrict__ W_root,
    const float* __restrict__ W_dec,
    unsigned short* __restrict__ Bt, unsigned short* __restrict__ Wdt,
    int* __restrict__ bucketcur, int NZ)
{
    const int idx = blockIdx.x * 256 + threadIdx.x;   // 0..24575
    if (idx < NZ) bucketcur[idx] = 0;
    if (idx < 16384) {
        const int k = idx >> 7;      // 0..127
        const int c = idx & 127;     // 0..127
        const float v = (c < HID) ? W_rel[(size_t)k * HID + c]
                                  : W_root[(size_t)k * HID + (c - HID)];
        Bt[(size_t)c * 128 + k] = bf16of(v);
    } else if (idx < 24576) {
        const int j = idx - 16384;
        const int k = j >> 7;        // 0..63
        const int c = j & 127;       // 0..127
        Wdt[(size_t)c * 64 + k] = bf16of(W_dec[(size_t)k * IN_CH + c]);
    }
}

// ---------------------------------------------------------------------------
// Kernel 1: LDS-free MFMA encoder + co-resident bucket scatter (R20 proven).
// Operand-swapped MFMA -> D=(x@W)^T -> lane owns one node, 4 contiguous
// output cols per ct -> vector epilogue stores.
// ---------------------------------------------------------------------------
__global__ __launch_bounds__(512) void graphmae_encode_scatter(
    const float* __restrict__ x, const unsigned short* __restrict__ Bt,
    const float* __restrict__ b_rel, const int* __restrict__ ei,
    unsigned short* __restrict__ y16, float* __restrict__ agg,
    int* __restrict__ bucketcur, unsigned int* __restrict__ sorted,
    int* __restrict__ spillcnt, int2* __restrict__ spill,
    int N, int E, int NBUK, int CE)
{
    __shared__ int lh[256];    // scatter: per-bucket local count
    __shared__ int lcur[256];  // scatter: reserved base -> running cursor

    const int t  = threadIdx.x;
    const int n0 = blockIdx.x * 64;
    const bool sduty = (blockIdx.x < NSCAT);
    const int e0 = blockIdx.x * CE;
    const int e1 = sduty ? min(E, e0 + CE) : 0;

    if (t >= 256) { lh[t - 256] = 0; lcur[t - 256] = 0; }
    __syncthreads();   // B1: lh zeroed

    if (t < 256) {
        const int w    = t >> 6;
        const int lane = t & 63;
        const int mr   = lane & 15;
        const int kg   = lane >> 4;
        const int nrow = n0 + w * 16 + mr;   // this lane's node (D col)

        v8s xfrag[4];
        #pragma unroll
        for (int ks = 0; ks < 4; ++ks) {
            uint4 pk = make_uint4(0u, 0u, 0u, 0u);
            if (nrow < N) {
                const float* xp = x + (size_t)nrow * IN_CH + ks * 32 + kg * 8;
                const float4 u0 = *(const float4*)(xp);
                const float4 u1 = *(const float4*)(xp + 4);
                pk = make_uint4(bf16pair(u0.x, u0.y), bf16pair(u0.z, u0.w),
                                bf16pair(u1.x, u1.y), bf16pair(u1.z, u1.w));
            }
            xfrag[ks] = *(v8s*)&pk;
        }

        #pragma unroll
        for (int ct = 0; ct < 8; ++ct) {
            v4f acc = {0.f, 0.f, 0.f, 0.f};
            const unsigned short* bp = Bt + (size_t)(ct * 16 + mr) * 128 + kg * 8;
            #pragma unroll
            for (int ks = 0; ks < 4; ++ks) {
                const v8s b = *(const v8s*)(bp + ks * 32);
                acc = __builtin_amdgcn_mfma_f32_16x16x32_bf16(b, xfrag[ks], acc, 0, 0, 0);
            }
            if (nrow < N) {
                if (ct < 4) {
                    const int c = ct * 16 + kg * 4;
                    *(uint2*)(y16 + (size_t)nrow * HID + c) =
                        make_uint2(bf16pair(acc[0], acc[1]), bf16pair(acc[2], acc[3]));
                } else {
                    const int c = (ct - 4) * 16 + kg * 4;
                    const float4 br = *(const float4*)(b_rel + c);
                    *(float4*)(agg + (size_t)nrow * HID + c) =
                        make_float4(acc[0] + br.x, acc[1] + br.y,
                                    acc[2] + br.z, acc[3] + br.w);
                }
            }
        }
    } else if (sduty) {
        for (int e = e0 + (t - 256); e < e1; e += 256)
            atomicAdd(&lh[ei[E + e] >> 8], 1);
    }
    __syncthreads();   // B2: hist complete

    if (t >= 256 && sduty) {
        const int b = t - 256;
        if (b < NBUK) {
            const int cnt = lh[b];
            if (cnt > 0) lcur[b] = atomicAdd(&bucketcur[b], cnt);
        }
    }
    __syncthreads();   // B3: cursors ready

    if (t >= 256 && sduty) {
        for (int e = e0 + (t - 256); e < e1; e += 256) {
            const int d = ei[E + e];
            const int s = ei[e];
            const int b = d >> 8;
            const int pos = atomicAdd(&lcur[b], 1);
            if (pos < BCAP) {
                sorted[(size_t)b * BCAP + pos] =
                    ((unsigned)(d & 255) << 16) | (unsigned)s;
            } else {
                const int p = atomicAdd(spillcnt, 1);   // statistically never
                if (p < SPILLCAP) spill[p] = make_int2(d, s);
            }
        }
    }
}

// ---------------------------------------------------------------------------
// Kernel 2: FUSED bucket-fill + gather + DECODE. Grid = NBUK x 8; block
// (b, split) owns 32 nodes.
//  Phase 1: scan bucket segment, build ELL rows in LDS (R21 proven).
//  Phase 2: 4 waves x 8 nodes gather; h = relu(agg+sum) -> LDS hs[32][72]
//           (bf16, padded: write conflict-free, read 2-way = free).
//  Phase 3: operand-swapped MFMA decode (R20 proven layout) straight from
//           hs -> out. Kills the h16 global round-trip + decode dispatch.
// ---------------------------------------------------------------------------
__global__ __launch_bounds__(256) void bucket_gather_decode(
    const unsigned int* __restrict__ sorted, const int* __restrict__ bucketcur,
    const unsigned short* __restrict__ y16, const float* __restrict__ agg,
    const int* __restrict__ spillcnt, const int2* __restrict__ spill,
    const unsigned short* __restrict__ Wdt, const float* __restrict__ b_dec,
    float* __restrict__ out, int N)
{
    __shared__ unsigned short sl[32 * ELLW];   // 2KB slot lists
    __shared__ int cnt[32];
    __shared__ int lsp[LSPCAP];                // local overflow: (dl<<16)|s
    __shared__ int lspcnt;
    __shared__ unsigned short hs[32][72];      // h rows bf16, padded (+8)

    const int t   = threadIdx.x;
    const int b   = blockIdx.x >> 3;     // bucket
    const int spl = blockIdx.x & 7;      // split
    const int dlo = spl * 32;            // own local-dst range [dlo, dlo+32)

    if (t < 32) cnt[t] = 0;
    if (t == 32) lspcnt = 0;
    __syncthreads();

    // ---- phase 1: scan bucket segment, keep own nodes ----
    const int m = min(bucketcur[b], BCAP);
    const unsigned int* src = sorted + (size_t)b * BCAP;
    for (int i = t; i < m; i += 256) {
        const unsigned int v = src[i];
        const int dl = (int)(v >> 16) - dlo;
        if ((unsigned)dl < 32u) {
            const int r = atomicAdd(&cnt[dl], 1);
            if (r < ELLW) {
                sl[dl * ELLW + r] = (unsigned short)(v & 0xffffu);
            } else {
                const int p = atomicAdd(&lspcnt, 1);   // P ~ 2e-3 graph-wide
                if (p < LSPCAP) lsp[p] = (dl << 16) | (int)(v & 0xffffu);
            }
        }
    }
    __syncthreads();

    // ---- phase 2: 4 waves x 8 nodes, gather; h -> hs ----
    const int wid  = t >> 6;
    const int lane = t & 63;
    const int es   = lane >> 3;   // edge slot 0..7
    const int cl   = lane & 7;    // col group: cols cl*8 .. cl*8+7
    const int lspN = min(lspcnt, LSPCAP);
    const int spN  = min(*spillcnt, SPILLCAP);

    for (int j = 0; j < 8; ++j) {
        const int dl = wid * 8 + j;          // local node 0..31
        const int n  = (b << 8) + dlo + dl;
        if (n >= N) continue;                // wave-uniform
        const int c_ = min(cnt[dl], ELLW);
        const unsigned short* sp = sl + dl * ELLW;

        float4 a0 = make_float4(0.f, 0.f, 0.f, 0.f);
        float4 a1 = make_float4(0.f, 0.f, 0.f, 0.f);
        if (es == 0) {
            a0 = *(const float4*)(agg + (size_t)n * HID + cl * 8);
            a1 = *(const float4*)(agg + (size_t)n * HID + cl * 8 + 4);
        }

        float acc[8];
        #pragma unroll
        for (int q = 0; q < 8; ++q) acc[q] = 0.f;

        for (int e = es; e < c_; e += 8) {
            const int s = sp[e];
            const uint4 v = *(const uint4*)(y16 + (size_t)s * HID + cl * 8);
            acc[0] += __uint_as_float(v.x << 16);
            acc[1] += __uint_as_float(v.x & 0xffff0000u);
            acc[2] += __uint_as_float(v.y << 16);
            acc[3] += __uint_as_float(v.y & 0xffff0000u);
            acc[4] += __uint_as_float(v.z << 16);
            acc[5] += __uint_as_float(v.z & 0xffff0000u);
            acc[6] += __uint_as_float(v.w << 16);
            acc[7] += __uint_as_float(v.w & 0xffff0000u);
        }
        for (int i = es; i < lspN; i += 8) {
            const int e2 = lsp[i];
            if ((e2 >> 16) == dl) {
                const int s = e2 & 0xffff;
                const uint4 v = *(const uint4*)(y16 + (size_t)s * HID + cl * 8);
                acc[0] += __uint_as_float(v.x << 16);
                acc[1] += __uint_as_float(v.x & 0xffff0000u);
                acc[2] += __uint_as_float(v.y << 16);
                acc[3] += __uint_as_float(v.y & 0xffff0000u);
                acc[4] += __uint_as_float(v.z << 16);
                acc[5] += __uint_as_float(v.z & 0xffff0000u);
                acc[6] += __uint_as_float(v.w << 16);
                acc[7] += __uint_as_float(v.w & 0xffff0000u);
            }
        }
        for (int i = es; i < spN; i += 8) {
            const int2 e2 = spill[i];
            if (e2.x == n) {
                const uint4 v = *(const uint4*)(y16 + (size_t)e2.y * HID + cl * 8);
                acc[0] += __uint_as_float(v.x << 16);
                acc[1] += __uint_as_float(v.x & 0xffff0000u);
                acc[2] += __uint_as_float(v.y << 16);
                acc[3] += __uint_as_float(v.y & 0xffff0000u);
                acc[4] += __uint_as_float(v.z << 16);
                acc[5] += __uint_as_float(v.z & 0xffff0000u);
                acc[6] += __uint_as_float(v.w << 16);
                acc[7] += __uint_as_float(v.w & 0xffff0000u);
            }
        }

        #pragma unroll
        for (int mk = 8; mk <= 32; mk <<= 1) {
            #pragma unroll
            for (int q = 0; q < 8; ++q) acc[q] += __shfl_xor(acc[q], mk);
        }

        if (es == 0) {
            const float h0 = fmaxf(a0.x + acc[0], 0.f);
            const float h1 = fmaxf(a0.y + acc[1], 0.f);
            const float h2 = fmaxf(a0.z + acc[2], 0.f);
            const float h3 = fmaxf(a0.w + acc[3], 0.f);
            const float h4 = fmaxf(a1.x + acc[4], 0.f);
            const float h5 = fmaxf(a1.y + acc[5], 0.f);
            const float h6 = fmaxf(a1.z + acc[6], 0.f);
            const float h7 = fmaxf(a1.w + acc[7], 0.f);
            uint4 o;
            o.x = bf16pair(h0, h1);
            o.y = bf16pair(h2, h3);
            o.z = bf16pair(h4, h5);
            o.w = bf16pair(h6, h7);
            *(uint4*)(&hs[dl][cl * 8]) = o;
        }
    }
    __syncthreads();   // hs complete

    // ---- phase 3: decode MFMA from hs (R20 proven operand-swapped form) ----
    // wave w: node-tile (w&1) [16 nodes], col-tiles (w>>1)*4 .. +3.
    const int mr   = lane & 15;
    const int kg   = lane >> 4;
    const int tile = wid & 1;
    const int ct0  = (wid >> 1) * 4;
    const int nrow = (b << 8) + dlo + tile * 16 + mr;

    v8s hfrag[2];
    #pragma unroll
    for (int ks = 0; ks < 2; ++ks)
        hfrag[ks] = *(const v8s*)(&hs[tile * 16 + mr][ks * 32 + kg * 8]);

    #pragma unroll
    for (int ct = ct0; ct < ct0 + 4; ++ct) {
        v4f acc = {0.f, 0.f, 0.f, 0.f};
        const unsigned short* wp = Wdt + (size_t)(ct * 16 + mr) * 64 + kg * 8;
        #pragma unroll
        for (int ks = 0; ks < 2; ++ks) {
            const v8s bb = *(const v8s*)(wp + ks * 32);
            acc = __builtin_amdgcn_mfma_f32_16x16x32_bf16(bb, hfrag[ks], acc, 0, 0, 0);
        }
        if (nrow < N) {
            const int c = ct * 16 + kg * 4;
            const float4 bd = *(const float4*)(b_dec + c);
            *(float4*)(out + (size_t)nrow * IN_CH + c) =
                make_float4(acc[0] + bd.x, acc[1] + bd.y,
                            acc[2] + bd.z, acc[3] + bd.w);
        }
    }
}

// ---------------------------------------------------------------------------
extern "C" void kernel_launch(void* const* d_in, const int* in_sizes, int n_in,
                              void* d_out, int out_size, void* d_ws, size_t ws_size,
                              hipStream_t stream)
{
    const float* x      = (const float*)d_in[0];
    const int*   ei     = (const int*)  d_in[1];   // [2][E] int32
    const float* W_rel  = (const float*)d_in[2];
    const float* b_rel  = (const float*)d_in[3];
    const float* W_root = (const float*)d_in[4];
    const float* W_dec  = (const float*)d_in[5];
    const float* b_dec  = (const float*)d_in[6];
    float* out = (float*)d_out;

    const int N = in_sizes[0] / IN_CH;
    const int E = in_sizes[1] / 2;

    const int NBUK = (N + 255) / 256;      // 196 buckets (dst>>8)
    const int CE   = (E + NSCAT - 1) / NSCAT;

    unsigned short* y16 = (unsigned short*)d_ws;                   // [N][64] bf16
    float* agg          = (float*)(y16 + (size_t)N * HID);         // [N][64] f32
    unsigned int* sorted = (unsigned int*)(agg + (size_t)N * HID); // [NBUK*BCAP]
    int* bucketcur = (int*)(sorted + (size_t)NBUK * BCAP);         // [NBUK]
    int* spillcnt  = bucketcur + NBUK;                             // [1]+pad
    int2* spill    = (int2*)(spillcnt + 3);                        // [SPILLCAP]
    unsigned short* Bt  = (unsigned short*)(spill + SPILLCAP);     // [128*128] bf16
    unsigned short* Wdt = Bt + 128 * 128;                          // [128*64] bf16

    const int nblk64 = (N + 63) / 64;   // 782 blocks (>= NSCAT)

    graphmae_prep<<<96, 256, 0, stream>>>(W_rel, W_root, W_dec, Bt, Wdt,
                                          bucketcur, NBUK + 1);

    graphmae_encode_scatter<<<nblk64, 512, 0, stream>>>(
        x, Bt, b_rel, ei, y16, agg,
        bucketcur, sorted, spillcnt, spill, N, E, NBUK, CE);

    bucket_gather_decode<<<NBUK * 8, 256, 0, stream>>>(
        sorted, bucketcur, y16, agg, spillcnt, spill, Wdt, b_dec, out, N);
}

// Round 23
// 70.906 us; speedup vs baseline: 1.2886x; 1.0085x over previous
//
#include <hip/hip_runtime.h>

#define IN_CH 128
#define HID 64
#define ELLW 32        // 32 slots per node row (in LDS)
#define SPILLCAP 4096  // global overflow edges (BCAP overflow; P ~ 0)
#define LSPCAP 128     // block-local ELL-overflow edges (deg>32)
#define NSCAT 256      // blocks carrying scatter duty
#define BCAP 3584      // fixed region capacity per 256-node bucket (mean 3061, +9 sigma)

typedef short v8s __attribute__((ext_vector_type(8)));   // 8 bf16 (4 VGPRs)
typedef float v4f __attribute__((ext_vector_type(4)));   // 4 f32 acc

// branch-free f32 -> bf16 (round-to-nearest-even), pure uint math
__device__ __forceinline__ unsigned int bf16pair(float a, float b) {
    unsigned int ua = __float_as_uint(a);
    unsigned int ub = __float_as_uint(b);
    ua = (ua + 0x7fffu + ((ua >> 16) & 1u)) >> 16;          // elem0 -> low 16
    ub = (ub + 0x7fffu + ((ub >> 16) & 1u)) & 0xffff0000u;  // elem1 -> high 16
    return ua | ub;
}
__device__ __forceinline__ unsigned short bf16of(float a) {
    unsigned int ua = __float_as_uint(a);
    return (unsigned short)((ua + 0x7fffu + ((ua >> 16) & 1u)) >> 16);
}

// ---------------------------------------------------------------------------
// Kernel 0: prep. Bt = [W_rel|W_root]^T (bf16 [c:128][k:128], 32KB) and
// Wdt = W_dec^T (bf16 [c:128][k:64], 16KB). Zeroes bucketcur+spillcnt.
// ---------------------------------------------------------------------------
__global__ __launch_bounds__(256) void graphmae_prep(
    const float* __restrict__ W_rel, const float* __restrict__ W_root,
    const float* __restrict__ W_dec,
    unsigned short* __restrict__ Bt, unsigned short* __restrict__ Wdt,
    int* __restrict__ bucketcur, int NZ)
{
    const int idx = blockIdx.x * 256 + threadIdx.x;   // 0..24575
    if (idx < NZ) bucketcur[idx] = 0;
    if (idx < 16384) {
        const int k = idx >> 7;      // 0..127
        const int c = idx & 127;     // 0..127
        const float v = (c < HID) ? W_rel[(size_t)k * HID + c]
                                  : W_root[(size_t)k * HID + (c - HID)];
        Bt[(size_t)c * 128 + k] = bf16of(v);
    } else if (idx < 24576) {
        const int j = idx - 16384;
        const int k = j >> 7;        // 0..63
        const int c = j & 127;       // 0..127
        Wdt[(size_t)c * 64 + k] = bf16of(W_dec[(size_t)k * IN_CH + c]);
    }
}

// ---------------------------------------------------------------------------
// Kernel 1: LDS-free MFMA encoder + co-resident bucket scatter (R20/R22
// proven). Operand-swapped MFMA -> D=(x@W)^T -> lane owns one node, 4
// contiguous output cols per ct -> vector epilogue stores.
// NEW (R23): agg stored bf16 (was f32) — halves the agg round-trip.
// ---------------------------------------------------------------------------
__global__ __launch_bounds__(512) void graphmae_encode_scatter(
    const float* __restrict__ x, const unsigned short* __restrict__ Bt,
    const float* __restrict__ b_rel, const int* __restrict__ ei,
    unsigned short* __restrict__ y16, unsigned short* __restrict__ agg16,
    int* __restrict__ bucketcur, unsigned int* __restrict__ sorted,
    int* __restrict__ spillcnt, int2* __restrict__ spill,
    int N, int E, int NBUK, int CE)
{
    __shared__ int lh[256];    // scatter: per-bucket local count
    __shared__ int lcur[256];  // scatter: reserved base -> running cursor

    const int t  = threadIdx.x;
    const int n0 = blockIdx.x * 64;
    const bool sduty = (blockIdx.x < NSCAT);
    const int e0 = blockIdx.x * CE;
    const int e1 = sduty ? min(E, e0 + CE) : 0;

    if (t >= 256) { lh[t - 256] = 0; lcur[t - 256] = 0; }
    __syncthreads();   // B1: lh zeroed

    if (t < 256) {
        const int w    = t >> 6;
        const int lane = t & 63;
        const int mr   = lane & 15;
        const int kg   = lane >> 4;
        const int nrow = n0 + w * 16 + mr;   // this lane's node (D col)

        v8s xfrag[4];
        #pragma unroll
        for (int ks = 0; ks < 4; ++ks) {
            uint4 pk = make_uint4(0u, 0u, 0u, 0u);
            if (nrow < N) {
                const float* xp = x + (size_t)nrow * IN_CH + ks * 32 + kg * 8;
                const float4 u0 = *(const float4*)(xp);
                const float4 u1 = *(const float4*)(xp + 4);
                pk = make_uint4(bf16pair(u0.x, u0.y), bf16pair(u0.z, u0.w),
                                bf16pair(u1.x, u1.y), bf16pair(u1.z, u1.w));
            }
            xfrag[ks] = *(v8s*)&pk;
        }

        #pragma unroll
        for (int ct = 0; ct < 8; ++ct) {
            v4f acc = {0.f, 0.f, 0.f, 0.f};
            const unsigned short* bp = Bt + (size_t)(ct * 16 + mr) * 128 + kg * 8;
            #pragma unroll
            for (int ks = 0; ks < 4; ++ks) {
                const v8s b = *(const v8s*)(bp + ks * 32);
                acc = __builtin_amdgcn_mfma_f32_16x16x32_bf16(b, xfrag[ks], acc, 0, 0, 0);
            }
            if (nrow < N) {
                if (ct < 4) {
                    const int c = ct * 16 + kg * 4;
                    *(uint2*)(y16 + (size_t)nrow * HID + c) =
                        make_uint2(bf16pair(acc[0], acc[1]), bf16pair(acc[2], acc[3]));
                } else {
                    const int c = (ct - 4) * 16 + kg * 4;
                    const float4 br = *(const float4*)(b_rel + c);
                    *(uint2*)(agg16 + (size_t)nrow * HID + c) =
                        make_uint2(bf16pair(acc[0] + br.x, acc[1] + br.y),
                                   bf16pair(acc[2] + br.z, acc[3] + br.w));
                }
            }
        }
    } else if (sduty) {
        for (int e = e0 + (t - 256); e < e1; e += 256)
            atomicAdd(&lh[ei[E + e] >> 8], 1);
    }
    __syncthreads();   // B2: hist complete

    if (t >= 256 && sduty) {
        const int b = t - 256;
        if (b < NBUK) {
            const int cnt = lh[b];
            if (cnt > 0) lcur[b] = atomicAdd(&bucketcur[b], cnt);
        }
    }
    __syncthreads();   // B3: cursors ready

    if (t >= 256 && sduty) {
        for (int e = e0 + (t - 256); e < e1; e += 256) {
            const int d = ei[E + e];
            const int s = ei[e];
            const int b = d >> 8;
            const int pos = atomicAdd(&lcur[b], 1);
            if (pos < BCAP) {
                sorted[(size_t)b * BCAP + pos] =
                    ((unsigned)(d & 255) << 16) | (unsigned)s;
            } else {
                const int p = atomicAdd(spillcnt, 1);   // statistically never
                if (p < SPILLCAP) spill[p] = make_int2(d, s);
            }
        }
    }
}

// ---------------------------------------------------------------------------
// Kernel 2: FUSED bucket-fill + gather + decode (R22 proven structure).
// NEW (R23): agg read as bf16.
// ---------------------------------------------------------------------------
__global__ __launch_bounds__(256) void bucket_gather_decode(
    const unsigned int* __restrict__ sorted, const int* __restrict__ bucketcur,
    const unsigned short* __restrict__ y16, const unsigned short* __restrict__ agg16,
    const int* __restrict__ spillcnt, const int2* __restrict__ spill,
    const unsigned short* __restrict__ Wdt, const float* __restrict__ b_dec,
    float* __restrict__ out, int N)
{
    __shared__ unsigned short sl[32 * ELLW];   // 2KB slot lists
    __shared__ int cnt[32];
    __shared__ int lsp[LSPCAP];                // local overflow: (dl<<16)|s
    __shared__ int lspcnt;
    __shared__ unsigned short hs[32][72];      // h rows bf16, padded (+8)

    const int t   = threadIdx.x;
    const int b   = blockIdx.x >> 3;     // bucket
    const int spl = blockIdx.x & 7;      // split
    const int dlo = spl * 32;            // own local-dst range [dlo, dlo+32)

    if (t < 32) cnt[t] = 0;
    if (t == 32) lspcnt = 0;
    __syncthreads();

    // ---- phase 1: scan bucket segment, keep own nodes ----
    const int m = min(bucketcur[b], BCAP);
    const unsigned int* src = sorted + (size_t)b * BCAP;
    for (int i = t; i < m; i += 256) {
        const unsigned int v = src[i];
        const int dl = (int)(v >> 16) - dlo;
        if ((unsigned)dl < 32u) {
            const int r = atomicAdd(&cnt[dl], 1);
            if (r < ELLW) {
                sl[dl * ELLW + r] = (unsigned short)(v & 0xffffu);
            } else {
                const int p = atomicAdd(&lspcnt, 1);   // P ~ 2e-3 graph-wide
                if (p < LSPCAP) lsp[p] = (dl << 16) | (int)(v & 0xffffu);
            }
        }
    }
    __syncthreads();

    // ---- phase 2: 4 waves x 8 nodes, gather; h -> hs ----
    const int wid  = t >> 6;
    const int lane = t & 63;
    const int es   = lane >> 3;   // edge slot 0..7
    const int cl   = lane & 7;    // col group: cols cl*8 .. cl*8+7
    const int lspN = min(lspcnt, LSPCAP);
    const int spN  = min(*spillcnt, SPILLCAP);

    for (int j = 0; j < 8; ++j) {
        const int dl = wid * 8 + j;          // local node 0..31
        const int n  = (b << 8) + dlo + dl;
        if (n >= N) continue;                // wave-uniform
        const int c_ = min(cnt[dl], ELLW);
        const unsigned short* sp = sl + dl * ELLW;

        // early independent agg read (bf16, only writer lanes)
        uint4 av = make_uint4(0u, 0u, 0u, 0u);
        if (es == 0) av = *(const uint4*)(agg16 + (size_t)n * HID + cl * 8);

        float acc[8];
        #pragma unroll
        for (int q = 0; q < 8; ++q) acc[q] = 0.f;

        for (int e = es; e < c_; e += 8) {
            const int s = sp[e];
            const uint4 v = *(const uint4*)(y16 + (size_t)s * HID + cl * 8);
            acc[0] += __uint_as_float(v.x << 16);
            acc[1] += __uint_as_float(v.x & 0xffff0000u);
            acc[2] += __uint_as_float(v.y << 16);
            acc[3] += __uint_as_float(v.y & 0xffff0000u);
            acc[4] += __uint_as_float(v.z << 16);
            acc[5] += __uint_as_float(v.z & 0xffff0000u);
            acc[6] += __uint_as_float(v.w << 16);
            acc[7] += __uint_as_float(v.w & 0xffff0000u);
        }
        for (int i = es; i < lspN; i += 8) {
            const int e2 = lsp[i];
            if ((e2 >> 16) == dl) {
                const int s = e2 & 0xffff;
                const uint4 v = *(const uint4*)(y16 + (size_t)s * HID + cl * 8);
                acc[0] += __uint_as_float(v.x << 16);
                acc[1] += __uint_as_float(v.x & 0xffff0000u);
                acc[2] += __uint_as_float(v.y << 16);
                acc[3] += __uint_as_float(v.y & 0xffff0000u);
                acc[4] += __uint_as_float(v.z << 16);
                acc[5] += __uint_as_float(v.z & 0xffff0000u);
                acc[6] += __uint_as_float(v.w << 16);
                acc[7] += __uint_as_float(v.w & 0xffff0000u);
            }
        }
        for (int i = es; i < spN; i += 8) {
            const int2 e2 = spill[i];
            if (e2.x == n) {
                const uint4 v = *(const uint4*)(y16 + (size_t)e2.y * HID + cl * 8);
                acc[0] += __uint_as_float(v.x << 16);
                acc[1] += __uint_as_float(v.x & 0xffff0000u);
                acc[2] += __uint_as_float(v.y << 16);
                acc[3] += __uint_as_float(v.y & 0xffff0000u);
                acc[4] += __uint_as_float(v.z << 16);
                acc[5] += __uint_as_float(v.z & 0xffff0000u);
                acc[6] += __uint_as_float(v.w << 16);
                acc[7] += __uint_as_float(v.w & 0xffff0000u);
            }
        }

        #pragma unroll
        for (int mk = 8; mk <= 32; mk <<= 1) {
            #pragma unroll
            for (int q = 0; q < 8; ++q) acc[q] += __shfl_xor(acc[q], mk);
        }

        if (es == 0) {
            const float h0 = fmaxf(__uint_as_float(av.x << 16)          + acc[0], 0.f);
            const float h1 = fmaxf(__uint_as_float(av.x & 0xffff0000u) + acc[1], 0.f);
            const float h2 = fmaxf(__uint_as_float(av.y << 16)          + acc[2], 0.f);
            const float h3 = fmaxf(__uint_as_float(av.y & 0xffff0000u) + acc[3], 0.f);
            const float h4 = fmaxf(__uint_as_float(av.z << 16)          + acc[4], 0.f);
            const float h5 = fmaxf(__uint_as_float(av.z & 0xffff0000u) + acc[5], 0.f);
            const float h6 = fmaxf(__uint_as_float(av.w << 16)          + acc[6], 0.f);
            const float h7 = fmaxf(__uint_as_float(av.w & 0xffff0000u) + acc[7], 0.f);
            uint4 o;
            o.x = bf16pair(h0, h1);
            o.y = bf16pair(h2, h3);
            o.z = bf16pair(h4, h5);
            o.w = bf16pair(h6, h7);
            *(uint4*)(&hs[dl][cl * 8]) = o;
        }
    }
    __syncthreads();   // hs complete

    // ---- phase 3: decode MFMA from hs (R20/R22 proven form) ----
    const int mr   = lane & 15;
    const int kg   = lane >> 4;
    const int tile = wid & 1;
    const int ct0  = (wid >> 1) * 4;
    const int nrow = (b << 8) + dlo + tile * 16 + mr;

    v8s hfrag[2];
    #pragma unroll
    for (int ks = 0; ks < 2; ++ks)
        hfrag[ks] = *(const v8s*)(&hs[tile * 16 + mr][ks * 32 + kg * 8]);

    #pragma unroll
    for (int ct = ct0; ct < ct0 + 4; ++ct) {
        v4f acc = {0.f, 0.f, 0.f, 0.f};
        const unsigned short* wp = Wdt + (size_t)(ct * 16 + mr) * 64 + kg * 8;
        #pragma unroll
        for (int ks = 0; ks < 2; ++ks) {
            const v8s bb = *(const v8s*)(wp + ks * 32);
            acc = __builtin_amdgcn_mfma_f32_16x16x32_bf16(bb, hfrag[ks], acc, 0, 0, 0);
        }
        if (nrow < N) {
            const int c = ct * 16 + kg * 4;
            const float4 bd = *(const float4*)(b_dec + c);
            *(float4*)(out + (size_t)nrow * IN_CH + c) =
                make_float4(acc[0] + bd.x, acc[1] + bd.y,
                            acc[2] + bd.z, acc[3] + bd.w);
        }
    }
}

// ---------------------------------------------------------------------------
extern "C" void kernel_launch(void* const* d_in, const int* in_sizes, int n_in,
                              void* d_out, int out_size, void* d_ws, size_t ws_size,
                              hipStream_t stream)
{
    const float* x      = (const float*)d_in[0];
    const int*   ei     = (const int*)  d_in[1];   // [2][E] int32
    const float* W_rel  = (const float*)d_in[2];
    const float* b_rel  = (const float*)d_in[3];
    const float* W_root = (const float*)d_in[4];
    const float* W_dec  = (const float*)d_in[5];
    const float* b_dec  = (const float*)d_in[6];
    float* out = (float*)d_out;

    const int N = in_sizes[0] / IN_CH;
    const int E = in_sizes[1] / 2;

    const int NBUK = (N + 255) / 256;      // 196 buckets (dst>>8)
    const int CE   = (E + NSCAT - 1) / NSCAT;

    unsigned short* y16   = (unsigned short*)d_ws;                  // [N][64] bf16
    unsigned short* agg16 = y16 + (size_t)N * HID;                  // [N][64] bf16
    unsigned int* sorted  = (unsigned int*)(agg16 + (size_t)N * HID); // [NBUK*BCAP]
    int* bucketcur = (int*)(sorted + (size_t)NBUK * BCAP);          // [NBUK]
    int* spillcnt  = bucketcur + NBUK;                              // [1]+pad
    int2* spill    = (int2*)(spillcnt + 3);                         // [SPILLCAP]
    unsigned short* Bt  = (unsigned short*)(spill + SPILLCAP);      // [128*128] bf16
    unsigned short* Wdt = Bt + 128 * 128;                           // [128*64] bf16

    const int nblk64 = (N + 63) / 64;   // 782 blocks (>= NSCAT)

    graphmae_prep<<<96, 256, 0, stream>>>(W_rel, W_root, W_dec, Bt, Wdt,
                                          bucketcur, NBUK + 1);

    graphmae_encode_scatter<<<nblk64, 512, 0, stream>>>(
        x, Bt, b_rel, ei, y16, agg16,
        bucketcur, sorted, spillcnt, spill, N, E, NBUK, CE);

    bucket_gather_decode<<<NBUK * 8, 256, 0, stream>>>(
        sorted, bucketcur, y16, agg16, spillcnt, spill, Wdt, b_dec, out, N);
}